// Round 7
// baseline (1107.570 us; speedup 1.0000x reference)
//
#include <hip/hip_runtime.h>
#include <hip/hip_bf16.h>

typedef __bf16 bf16_t;
typedef __bf16 bf16x4 __attribute__((ext_vector_type(4)));
typedef __bf16 bf16x8 __attribute__((ext_vector_type(8)));
typedef float f32x4 __attribute__((ext_vector_type(4)));

#define BB 2
#define SS 4096
#define DD 1024
#define VV 32000
#define HH 8
#define CC 256
#define NC 16
#define QKVW 1280   // q(128) | k(128) | v(1024)

#define GLD_LDS16(gp, lp) __builtin_amdgcn_global_load_lds( \
    (const __attribute__((address_space(1))) void*)(gp),    \
    (__attribute__((address_space(3))) void*)(lp), 16, 0, 0)

// ---------------- ctx: emb gather + 4-tap causal sum ----------------
__global__ __launch_bounds__(256) void ctx_kernel(
    const int* __restrict__ x, const float* __restrict__ emb,
    float* __restrict__ ctx, bf16_t* __restrict__ ctxb)
{
  const int row = blockIdx.x;            // b*SS + s
  const int b = row >> 12, s = row & (SS - 1);
  const int t = threadIdx.x;             // d = t*4
  float4 a = make_float4(0.f, 0.f, 0.f, 0.f);
  #pragma unroll
  for (int o = 0; o < 4; ++o) {
    if (s - o >= 0) {
      const int idx = x[b * SS + s - o];
      const float4 e = *(const float4*)(emb + (size_t)idx * DD + t * 4);
      a.x += e.x; a.y += e.y; a.z += e.z; a.w += e.w;
    }
  }
  *(float4*)(ctx + (size_t)row * DD + t * 4) = a;
  bf16x4 bv;
  bv[0] = (__bf16)a.x; bv[1] = (__bf16)a.y; bv[2] = (__bf16)a.z; bv[3] = (__bf16)a.w;
  *(bf16x4*)(ctxb + (size_t)row * DD + t * 4) = bv;
}

// ---------------- transpose + f32->bf16: dst[c][r] = src[r][c] ----------------
__global__ __launch_bounds__(256) void transpose_cvt(
    const float* __restrict__ src, bf16_t* __restrict__ dst,
    int srcRows, int srcCols)
{
  __shared__ __align__(16) float tile[64][65];
  const int c0 = blockIdx.x * 64, r0 = blockIdx.y * 64;
  const int tc = threadIdx.x & 63, tq = threadIdx.x >> 6;
  #pragma unroll
  for (int k = 0; k < 16; ++k) {
    const int r = k * 4 + tq;
    tile[r][tc] = src[(size_t)(r0 + r) * srcCols + c0 + tc];
  }
  __syncthreads();
  #pragma unroll
  for (int k = 0; k < 16; ++k) {
    const int cO = k * 4 + tq;
    dst[(size_t)(c0 + cO) * srcRows + r0 + tc] = (__bf16)tile[tc][cO];
  }
}

// ================= 256x256 tile, BK=64, 8-wave, pipelined GEMM ==============
// C[M,N] = A[M,K] @ BT[N,K]^T.  EPI: 0=none, 1=+bias[col], 2=+res, 3=phi(col<256)
// R7: read-ahead pipelining. R6 showed FETCH fixed but time flat: per-phase
// {reads; barrier; lgkmcnt(0); MFMA; barrier} serializes LDS reads against
// MFMA (~770cy/K-tile) + 8 barriers. Now each read batch is issued one phase
// early and waited with a COUNTED lgkmcnt next phase:
//   q0: bar; rd B23[k](4);  stg AQ13[k+1]; lgkm(4);  MFMA afA x bfr01
//   q1: bar; rd A_MH1[k](8); stg BNH1[k+1]; lgkm(8); MFMA afA x bfr23
//   q2: bar; stg AQ02[k+2];                lgkm(0);  MFMA afB x bfr01
//   q3: bar; stg BNH0[k+2]; vmcnt(4); bar2;          // k+1 globally staged
//       rd A_MH0[k+1]->afA(8) + B01[k+1]->bfr01(4);  MFMA afB x bfr23
// bar2 is required: read-ahead reads regions staged by OTHER waves' gld_lds;
// only (all waves' vmcnt)+barrier makes tile k+1 globally visible.
// Tail: vmcnt(0) at k>=NT-2 (counted wait passes vacuously once staging stops).

#define STG_AQ02(SRC, RB, LDSB, KT) do {                                      \
  const size_t _k = (size_t)(KT) * 64;                                        \
  GLD_LDS16((SRC) + (size_t)((RB) + (t >> 3)) * K + _k + cg8,                 \
            (LDSB) + (size_t)(t & ~63) * 8);                                  \
  GLD_LDS16((SRC) + (size_t)((RB) + 128 + (t >> 3)) * K + _k + cg8,          \
            (LDSB) + 8192 + (size_t)(t & ~63) * 8);                           \
} while (0)

#define STG_AQ13(SRC, RB, LDSB, KT) do {                                      \
  const size_t _k = (size_t)(KT) * 64;                                        \
  GLD_LDS16((SRC) + (size_t)((RB) + 64 + (t >> 3)) * K + _k + cg8,           \
            (LDSB) + 4096 + (size_t)(t & ~63) * 8);                           \
  GLD_LDS16((SRC) + (size_t)((RB) + 192 + (t >> 3)) * K + _k + cg8,          \
            (LDSB) + 12288 + (size_t)(t & ~63) * 8);                          \
} while (0)

#define STG_BNH0(SRC, RB, LDSB, KT) do {                                      \
  const size_t _k = (size_t)(KT) * 64;                                        \
  const int _r = (t >> 3) + ((t >> 8) << 5);                                  \
  const int _u = ((t & ~63) + ((t >> 8) << 8)) * 8;                           \
  GLD_LDS16((SRC) + (size_t)((RB) + _r) * K + _k + cg8, (LDSB) + _u);        \
  GLD_LDS16((SRC) + (size_t)((RB) + 128 + _r) * K + _k + cg8,                \
            (LDSB) + 8192 + _u);                                              \
} while (0)

#define STG_BNH1(SRC, RB, LDSB, KT) do {                                      \
  const size_t _k = (size_t)(KT) * 64;                                        \
  const int _r = (t >> 3) + ((t >> 8) << 5);                                  \
  const int _u = ((t & ~63) + ((t >> 8) << 8)) * 8;                           \
  GLD_LDS16((SRC) + (size_t)((RB) + 32 + _r) * K + _k + cg8,                 \
            (LDSB) + 2048 + _u);                                              \
  GLD_LDS16((SRC) + (size_t)((RB) + 160 + _r) * K + _k + cg8,                \
            (LDSB) + 10240 + _u);                                             \
} while (0)

#define READ_ASET(DST, MH, BUF) do {                                          \
  _Pragma("unroll") for (int mi = 0; mi < 4; ++mi) {                          \
    const bf16_t* ap = (BUF) + (size_t)(wr * 128 + (MH) * 64 + mi * 16 + lr) * 64; \
    DST[mi][0] = *(const bf16x8*)(ap + c0);                                   \
    DST[mi][1] = *(const bf16x8*)(ap + c1);                                   \
  } } while (0)

#define READ_BPAIR(NB, BUF) do {                                              \
  _Pragma("unroll") for (int nj = 0; nj < 2; ++nj) {                          \
    const bf16_t* bp = (BUF) + (size_t)(wc * 64 + ((NB) + nj) * 16 + lr) * 64; \
    bfr[(NB) + nj][0] = *(const bf16x8*)(bp + c0);                            \
    bfr[(NB) + nj][1] = *(const bf16x8*)(bp + c1);                            \
  } } while (0)

#define MFMA8M(AF, MH, NB) do {                                               \
  _Pragma("unroll") for (int mi = 0; mi < 4; ++mi)                            \
    _Pragma("unroll") for (int nj = 0; nj < 2; ++nj) {                        \
      acc[(MH)*4+mi][(NB)+nj] = __builtin_amdgcn_mfma_f32_16x16x32_bf16(      \
          AF[mi][0], bfr[(NB)+nj][0], acc[(MH)*4+mi][(NB)+nj], 0, 0, 0);      \
      acc[(MH)*4+mi][(NB)+nj] = __builtin_amdgcn_mfma_f32_16x16x32_bf16(      \
          AF[mi][1], bfr[(NB)+nj][1], acc[(MH)*4+mi][(NB)+nj], 0, 0, 0);      \
    } } while (0)

#define LGKM_SB(N) do {                                                       \
  asm volatile("s_waitcnt lgkmcnt(" #N ")" ::: "memory");                     \
  __builtin_amdgcn_sched_barrier(0);                                          \
} while (0)

template<int EPI>
__global__ __launch_bounds__(512, 2) void gemm256_kernel(
    const bf16_t* __restrict__ A, const bf16_t* __restrict__ BT,
    float* __restrict__ C, const float* __restrict__ extra,
    int N, int K, int GX)
{
  __shared__ __align__(16) bf16_t AsBuf[2][256 * 64];
  __shared__ __align__(16) bf16_t BsBuf[2][256 * 64];
  // 2-D slab swizzle: XCD owns a 4-row A-slab; 32 CUs form 8bx x 4by cluster.
  const int nwg = gridDim.x;
  const int bid = blockIdx.x;
  const int GYl = nwg / GX;
  const int SLAB = GYl >> 3;
  const int xcd = bid & 7, i = bid >> 3;
  const int by = xcd * SLAB + (i % SLAB);
  const int bx = i / SLAB;
  const int n0 = bx * 256, m0 = by * 256;
  const int t = threadIdx.x;
  const int lane = t & 63, w = t >> 6;
  const int wr = w >> 2, wc = w & 3;
  const int lr = lane & 15, lq = lane >> 4;
  const int rx = lr & 7;
  const int c0 = ((0 + lq) ^ rx) * 8;                  // ks=0 read col (elems)
  const int c1 = ((4 + lq) ^ rx) * 8;                  // ks=1
  const int cg8 = (((t & 7) ^ ((t >> 3) & 7))) * 8;    // stage pre-swizzled col
  const int NT = K >> 6;                               // K-tiles
  f32x4 acc[8][4] = {};
  bf16x8 afA[4][2], afB[4][2], bfr[4][2];

  // prologue: stage tiles 0 + half of 1; drain to tile0; read-ahead tile0
  STG_AQ02(A,  m0, AsBuf[0], 0);
  STG_BNH0(BT, n0, BsBuf[0], 0);
  STG_AQ13(A,  m0, AsBuf[0], 0);
  STG_BNH1(BT, n0, BsBuf[0], 0);
  STG_AQ02(A,  m0, AsBuf[1], 1);
  STG_BNH0(BT, n0, BsBuf[1], 1);
  asm volatile("s_waitcnt vmcnt(4)" ::: "memory");
  __builtin_amdgcn_s_barrier();
  READ_ASET(afA, 0, AsBuf[0]);
  READ_BPAIR(0, BsBuf[0]);

  for (int k = 0; k < NT; ++k) {
    const bf16_t* Ac = AsBuf[k & 1];
    const bf16_t* Bc = BsBuf[k & 1];
    bf16_t* An = AsBuf[(k + 1) & 1];
    bf16_t* Bn = BsBuf[(k + 1) & 1];
    bf16_t* Ak = AsBuf[k & 1];
    bf16_t* Bk = BsBuf[k & 1];
    const bool s1 = (k + 1 < NT), s2 = (k + 2 < NT);
    // ---- q0: rd B23[k]; stage AQ13[k+1]; wait read-ahead (12 old)
    __builtin_amdgcn_s_barrier();
    READ_BPAIR(2, Bc);
    if (s1) STG_AQ13(A, m0, An, k + 1);
    LGKM_SB(4);
    __builtin_amdgcn_s_setprio(1);
    MFMA8M(afA, 0, 0);
    __builtin_amdgcn_s_setprio(0);
    // ---- q1: rd A_MH1[k]->afB; stage BNH1[k+1]; wait B23
    __builtin_amdgcn_s_barrier();
    READ_ASET(afB, 1, Ac);
    if (s1) STG_BNH1(BT, n0, Bn, k + 1);
    LGKM_SB(8);
    __builtin_amdgcn_s_setprio(1);
    MFMA8M(afA, 0, 2);
    __builtin_amdgcn_s_setprio(0);
    // ---- q2: stage AQ02[k+2]; wait afB
    __builtin_amdgcn_s_barrier();
    if (s2) STG_AQ02(A, m0, Ak, k + 2);
    LGKM_SB(0);
    __builtin_amdgcn_s_setprio(1);
    MFMA8M(afB, 1, 0);
    __builtin_amdgcn_s_setprio(0);
    // ---- q3: stage BNH0[k+2]; vmcnt; bar2 (k+1 globally staged); read-ahead
    __builtin_amdgcn_s_barrier();
    if (s2) STG_BNH0(BT, n0, Bk, k + 2);
    if (k < NT - 2) { asm volatile("s_waitcnt vmcnt(4)" ::: "memory"); }
    else            { asm volatile("s_waitcnt vmcnt(0)" ::: "memory"); }
    __builtin_amdgcn_s_barrier();
    if (s1) { READ_ASET(afA, 0, An); READ_BPAIR(0, Bn); }
    __builtin_amdgcn_sched_barrier(0);
    __builtin_amdgcn_s_setprio(1);
    MFMA8M(afB, 1, 2);
    __builtin_amdgcn_s_setprio(0);
  }

  // epilogue: C/D layout col=lane&15, row=(lane>>4)*4+reg  [m89-verified]
  // nontemporal: keep the C stream from evicting B out of L2/L3 (R6: -0.7GB FETCH)
  #pragma unroll
  for (int mi = 0; mi < 8; ++mi) {
    #pragma unroll
    for (int r = 0; r < 4; ++r) {
      const int row = m0 + wr * 128 + mi * 16 + lq * 4 + r;
      #pragma unroll
      for (int ni = 0; ni < 4; ++ni) {
        const int col = n0 + wc * 64 + ni * 16 + lr;
        float v = acc[mi][ni][r];
        if (EPI == 1) v += extra[col];
        if (EPI == 2) v += extra[(size_t)row * N + col];
        if (EPI == 3) { if (col < 256) v = v > 0.f ? v + 1.f : __expf(v); }
        __builtin_nontemporal_store(v, &C[(size_t)row * N + col]);
      }
    }
  }
}

// ---------------- per-chunk G = K^T V and ksum ----------------
__global__ __launch_bounds__(256) void gstate_kernel(
    const float* __restrict__ qkv, float* __restrict__ G, float* __restrict__ KS)
{
  const int g = blockIdx.x;                    // b*128 + c*8 + h
  const int h = g & 7, c = (g >> 3) & 15, b = g >> 7;
  const int t = threadIdx.x;
  const int i = t >> 4, dg = t & 15;           // k-index, 8-col group
  const int srcbase = b * SS + c * CC;
  __shared__ __align__(16) float k_lds[64][16];
  __shared__ __align__(16) float v_lds[64][128];
  float acc[8] = {0,0,0,0,0,0,0,0};
  float ks = 0.f;
  for (int st = 0; st < 4; ++st) {
    __syncthreads();
    { const int sl = t >> 2, i0 = (t & 3) * 4;
      *(float4*)&k_lds[sl][i0] =
        *(const float4*)(qkv + (size_t)(srcbase + st * 64 + sl) * QKVW + 128 + h * 16 + i0); }
    #pragma unroll
    for (int vv = 0; vv < 8; ++vv) {
      const int sl = (t >> 5) + vv * 8, col = (t & 31) * 4;
      *(float4*)&v_lds[sl][col] =
        *(const float4*)(qkv + (size_t)(srcbase + st * 64 + sl) * QKVW + 256 + h * 128 + col);
    }
    __syncthreads();
    for (int sl = 0; sl < 64; ++sl) {
      const float kv = k_lds[sl][i];
      if (dg == 0) ks += kv;
      const float4 va = *(const float4*)&v_lds[sl][dg * 8];
      const float4 vb = *(const float4*)&v_lds[sl][dg * 8 + 4];
      acc[0] = fmaf(kv, va.x, acc[0]); acc[1] = fmaf(kv, va.y, acc[1]);
      acc[2] = fmaf(kv, va.z, acc[2]); acc[3] = fmaf(kv, va.w, acc[3]);
      acc[4] = fmaf(kv, vb.x, acc[4]); acc[5] = fmaf(kv, vb.y, acc[5]);
      acc[6] = fmaf(kv, vb.z, acc[6]); acc[7] = fmaf(kv, vb.w, acc[7]);
    }
  }
  float* gp = G + ((size_t)(b * NC + c) * HH + h) * 2048 + i * 128 + dg * 8;
  *(float4*)gp       = make_float4(acc[0], acc[1], acc[2], acc[3]);
  *(float4*)(gp + 4) = make_float4(acc[4], acc[5], acc[6], acc[7]);
  if (dg == 0) KS[((size_t)(b * NC + c) * HH + h) * 16 + i] = ks;
}

// ---------------- attention: intra (masked) + bypass (prev chunk) + state ----------------
__global__ __launch_bounds__(256) void attn_kernel(
    const float* __restrict__ qkv, const float* __restrict__ Gb,
    const float* __restrict__ KS, bf16_t* __restrict__ outp)
{
  const int bid = blockIdx.x;                   // 512 = b*256 + c*16 + h*2 + dh
  const int dh = bid & 1, h = (bid >> 1) & 7, c = (bid >> 4) & 15, b = bid >> 8;
  const int t = threadIdx.x;
  const int cg = t & 3, rg = t >> 2;            // 16-col group, 4-row group
  const int rowbase = b * SS + c * CC;

  __shared__ __align__(16) float k_lds[64][16];
  __shared__ __align__(16) float v_lds[64][64];
  __shared__ __align__(16) float s_lds[16 * 64];
  __shared__ float z_lds[16];

  float q[4][16];
  #pragma unroll
  for (int rr = 0; rr < 4; ++rr) {
    const float* qp = qkv + (size_t)(rowbase + rg * 4 + rr) * QKVW + h * 16;
    #pragma unroll
    for (int i4 = 0; i4 < 4; ++i4) {
      const float4 qv = *(const float4*)(qp + i4 * 4);
      q[rr][i4*4+0] = qv.x; q[rr][i4*4+1] = qv.y; q[rr][i4*4+2] = qv.z; q[rr][i4*4+3] = qv.w;
    }
  }
  float acc[4][16] = {};
  float den[4] = {0.f, 0.f, 0.f, 0.f};

  for (int ph = 0; ph < 2; ++ph) {
    const int cc = c - ph;                       // ph0: current chunk (masked); ph1: prev chunk
    if (cc < 0) break;
    const int srcbase = b * SS + cc * CC;
    const bool masked = (ph == 0);
    for (int st = 0; st < 4; ++st) {
      __syncthreads();
      { const int sl = t >> 2, i0 = (t & 3) * 4;
        *(float4*)&k_lds[sl][i0] =
          *(const float4*)(qkv + (size_t)(srcbase + st * 64 + sl) * QKVW + 128 + h * 16 + i0); }
      #pragma unroll
      for (int vv = 0; vv < 4; ++vv) {
        const int sl = (t >> 4) + vv * 16, col = (t & 15) * 4;
        *(float4*)&v_lds[sl][col] =
          *(const float4*)(qkv + (size_t)(srcbase + st * 64 + sl) * QKVW + 256 + h * 128 + dh * 64 + col);
      }
      __syncthreads();
      for (int sl = 0; sl < 64; ++sl) {
        float kv[16], vvv[16];
        #pragma unroll
        for (int i4 = 0; i4 < 4; ++i4) {
          const float4 kf = *(const float4*)&k_lds[sl][i4 * 4];
          kv[i4*4+0] = kf.x; kv[i4*4+1] = kf.y; kv[i4*4+2] = kf.z; kv[i4*4+3] = kf.w;
          const float4 vf = *(const float4*)&v_lds[sl][cg * 16 + i4 * 4];
          vvv[i4*4+0] = vf.x; vvv[i4*4+1] = vf.y; vvv[i4*4+2] = vf.z; vvv[i4*4+3] = vf.w;
        }
        const int sidx = st * 64 + sl;
        #pragma unroll
        for (int rr = 0; rr < 4; ++rr) {
          float a = 0.f;
          #pragma unroll
          for (int i = 0; i < 16; ++i) a = fmaf(q[rr][i], kv[i], a);
          if (masked && sidx > rg * 4 + rr) a = 0.f;
          den[rr] += a;                          // intra: q.kcum ; bypass: q.bksum
          #pragma unroll
          for (int e = 0; e < 16; ++e) acc[rr][e] = fmaf(a, vvv[e], acc[rr][e]);
        }
      }
    }
  }

  if (c >= 2) {                                  // long-range state: sum_{j<=c-2} G_j
    float sa0 = 0.f, sa1 = 0.f, sa2 = 0.f, sa3 = 0.f;
    const int si = t >> 4, sc = (t & 15) * 4;
    for (int j = 0; j + 2 <= c; ++j) {
      const float4 gv = *(const float4*)(Gb + ((size_t)(b * NC + j) * HH + h) * 2048
                                            + si * 128 + dh * 64 + sc);
      sa0 += gv.x; sa1 += gv.y; sa2 += gv.z; sa3 += gv.w;
    }
    if (t < 16) {
      float z = 0.f;
      for (int j = 0; j + 2 <= c; ++j) z += KS[((size_t)(b * NC + j) * HH + h) * 16 + t];
      z_lds[t] = z;
    }
    *(float4*)&s_lds[si * 64 + sc] = make_float4(sa0, sa1, sa2, sa3);
    __syncthreads();
    #pragma unroll
    for (int i = 0; i < 16; ++i) {
      float sv[16];
      #pragma unroll
      for (int e4 = 0; e4 < 4; ++e4) {
        const float4 f = *(const float4*)&s_lds[i * 64 + cg * 16 + e4 * 4];
        sv[e4*4+0] = f.x; sv[e4*4+1] = f.y; sv[e4*4+2] = f.z; sv[e4*4+3] = f.w;
      }
      const float zi = z_lds[i];
      #pragma unroll
      for (int rr = 0; rr < 4; ++rr) {
        const float qv = q[rr][i];
        den[rr] = fmaf(qv, zi, den[rr]);
        #pragma unroll
        for (int e = 0; e < 16; ++e) acc[rr][e] = fmaf(qv, sv[e], acc[rr][e]);
      }
    }
  }

  const size_t obase = (size_t)rowbase * DD + h * 128 + dh * 64 + cg * 16;
  #pragma unroll
  for (int rr = 0; rr < 4; ++rr) {
    const float inv = 1.0f / (den[rr] + 1e-6f);
    bf16_t* op = outp + obase + (size_t)(rg * 4 + rr) * DD;
    #pragma unroll
    for (int e4 = 0; e4 < 4; ++e4) {
      bf16x4 bv;
      bv[0] = (__bf16)(acc[rr][e4*4+0] * inv); bv[1] = (__bf16)(acc[rr][e4*4+1] * inv);
      bv[2] = (__bf16)(acc[rr][e4*4+2] * inv); bv[3] = (__bf16)(acc[rr][e4*4+3] * inv);
      *(bf16x4*)(op + e4 * 4) = bv;
    }
  }
}

// ---------------- LayerNorm (eps 1e-5) -> bf16 ----------------
__global__ __launch_bounds__(256) void ln_kernel(
    const float* __restrict__ hbuf, const float* __restrict__ g,
    const float* __restrict__ bta, bf16_t* __restrict__ out)
{
  const int row = blockIdx.x;
  const int t = threadIdx.x;
  const float4 x = ((const float4*)(hbuf + (size_t)row * DD))[t];
  float s  = x.x + x.y + x.z + x.w;
  float s2 = x.x*x.x + x.y*x.y + x.z*x.z + x.w*x.w;
  #pragma unroll
  for (int off = 32; off > 0; off >>= 1) {
    s  += __shfl_down(s,  off, 64);
    s2 += __shfl_down(s2, off, 64);
  }
  __shared__ float ws[8];
  if ((t & 63) == 0) { ws[(t >> 6) * 2] = s; ws[(t >> 6) * 2 + 1] = s2; }
  __syncthreads();
  const float ts  = ws[0] + ws[2] + ws[4] + ws[6];
  const float ts2 = ws[1] + ws[3] + ws[5] + ws[7];
  const float mu  = ts * (1.0f / DD);
  const float var = ts2 * (1.0f / DD) - mu * mu;
  const float inv = rsqrtf(var + 1e-5f);
  const float4 gv = ((const float4*)g)[t];
  const float4 bv = ((const float4*)bta)[t];
  bf16x4 o;
  o[0] = (__bf16)((x.x - mu) * inv * gv.x + bv.x);
  o[1] = (__bf16)((x.y - mu) * inv * gv.y + bv.y);
  o[2] = (__bf16)((x.z - mu) * inv * gv.z + bv.z);
  o[3] = (__bf16)((x.w - mu) * inv * gv.w + bv.w);
  *(bf16x4*)(out + (size_t)row * DD + t * 4) = o;
}

extern "C" void kernel_launch(void* const* d_in, const int* in_sizes, int n_in,
                              void* d_out, int out_size, void* d_ws, size_t ws_size,
                              hipStream_t stream) {
  (void)in_sizes; (void)n_in; (void)out_size; (void)ws_size;
  const int*   x    = (const int*)d_in[0];
  const float* emb  = (const float*)d_in[1];
  const float* Wq   = (const float*)d_in[2];
  const float* Wk   = (const float*)d_in[3];
  const float* Wv   = (const float*)d_in[4];
  const float* Wo   = (const float*)d_in[5];
  const float* ln_g = (const float*)d_in[6];
  const float* ln_b = (const float*)d_in[7];
  const float* outW = (const float*)d_in[8];
  const float* outb = (const float*)d_in[9];
  float* out = (float*)d_out;

  char* ws = (char*)d_ws;
  float*  ctx_f32 = (float*) (ws + 0);            // 33,554,432
  bf16_t* ctx_bf  = (bf16_t*)(ws + 33554432ull);  // 16,777,216
  float*  qkv     = (float*) (ws + 50331648ull);  // 41,943,040 (reused as h f32)
  bf16_t* attn_bf = (bf16_t*)(ws + 92274688ull);  // 16,777,216 (reused as h bf16)
  float*  Gbuf    = (float*) (ws + 109051904ull); //  2,097,152
  float*  KSbuf   = (float*) (ws + 111149056ull); //     16,384
  bf16_t* WqkvT   = (bf16_t*)(ws + 111165440ull); //  2,621,440
  bf16_t* WoT     = (bf16_t*)(ws + 113786880ull); //  2,097,152
  bf16_t* outWT   = (bf16_t*)(ws + 115884032ull); // 65,536,000  (end 181,420,032)
  float*  hbuf    = qkv;
  bf16_t* h_bf    = attn_bf;

  transpose_cvt<<<dim3(2, 16),   256, 0, stream>>>(Wq,   WqkvT,              DD, 128);
  transpose_cvt<<<dim3(2, 16),   256, 0, stream>>>(Wk,   WqkvT + 128 * DD,   DD, 128);
  transpose_cvt<<<dim3(16, 16),  256, 0, stream>>>(Wv,   WqkvT + 256 * DD,   DD, DD);
  transpose_cvt<<<dim3(16, 16),  256, 0, stream>>>(Wo,   WoT,                DD, DD);
  transpose_cvt<<<dim3(500, 16), 256, 0, stream>>>(outW, outWT,              DD, VV);

  ctx_kernel<<<BB * SS, 256, 0, stream>>>(x, emb, ctx_f32, ctx_bf);

  // QKV projection + fused phi on cols<256  (M=8192, N=1280, grid 5*32=160)
  gemm256_kernel<3><<<(QKVW / 256) * (BB * SS / 256), 512, 0, stream>>>(
      ctx_bf, WqkvT, qkv, nullptr, QKVW, DD, QKVW / 256);

  gstate_kernel<<<BB * NC * HH, 256, 0, stream>>>(qkv, Gbuf, KSbuf);
  attn_kernel<<<BB * NC * HH * 2, 256, 0, stream>>>(qkv, Gbuf, KSbuf, attn_bf);

  // out-proj + residual  (N=1024, grid 4*32=128)
  gemm256_kernel<2><<<(DD / 256) * (BB * SS / 256), 512, 0, stream>>>(
      attn_bf, WoT, hbuf, ctx_f32, DD, DD, DD / 256);

  ln_kernel<<<BB * SS, 256, 0, stream>>>(hbuf, ln_g, ln_b, h_bf);

  // logits + bias  (N=32000, grid 125*32=4000)
  gemm256_kernel<1><<<(VV / 256) * (BB * SS / 256), 512, 0, stream>>>(
      h_bf, outWT, out, outb, VV, DD, VV / 256);
}

// Round 8
// 1053.308 us; speedup vs baseline: 1.0515x; 1.0515x over previous
//
#include <hip/hip_runtime.h>
#include <hip/hip_bf16.h>

typedef __bf16 bf16_t;
typedef __bf16 bf16x4 __attribute__((ext_vector_type(4)));
typedef __bf16 bf16x8 __attribute__((ext_vector_type(8)));
typedef float f32x4 __attribute__((ext_vector_type(4)));

#define BB 2
#define SS 4096
#define DD 1024
#define VV 32000
#define HH 8
#define CC 256
#define NC 16
#define QKVW 1280   // q(128) | k(128) | v(1024)

#define GLD_LDS16(gp, lp) __builtin_amdgcn_global_load_lds( \
    (const __attribute__((address_space(1))) void*)(gp),    \
    (__attribute__((address_space(3))) void*)(lp), 16, 0, 0)

// ---------------- ctx: emb gather + 4-tap causal sum ----------------
__global__ __launch_bounds__(256) void ctx_kernel(
    const int* __restrict__ x, const float* __restrict__ emb,
    float* __restrict__ ctx, bf16_t* __restrict__ ctxb)
{
  const int row = blockIdx.x;            // b*SS + s
  const int b = row >> 12, s = row & (SS - 1);
  const int t = threadIdx.x;             // d = t*4
  float4 a = make_float4(0.f, 0.f, 0.f, 0.f);
  #pragma unroll
  for (int o = 0; o < 4; ++o) {
    if (s - o >= 0) {
      const int idx = x[b * SS + s - o];
      const float4 e = *(const float4*)(emb + (size_t)idx * DD + t * 4);
      a.x += e.x; a.y += e.y; a.z += e.z; a.w += e.w;
    }
  }
  *(float4*)(ctx + (size_t)row * DD + t * 4) = a;
  bf16x4 bv;
  bv[0] = (__bf16)a.x; bv[1] = (__bf16)a.y; bv[2] = (__bf16)a.z; bv[3] = (__bf16)a.w;
  *(bf16x4*)(ctxb + (size_t)row * DD + t * 4) = bv;
}

// ---------------- transpose + f32->bf16: dst[c][r] = src[r][c] ----------------
__global__ __launch_bounds__(256) void transpose_cvt(
    const float* __restrict__ src, bf16_t* __restrict__ dst,
    int srcRows, int srcCols)
{
  __shared__ __align__(16) float tile[64][65];
  const int c0 = blockIdx.x * 64, r0 = blockIdx.y * 64;
  const int tc = threadIdx.x & 63, tq = threadIdx.x >> 6;
  #pragma unroll
  for (int k = 0; k < 16; ++k) {
    const int r = k * 4 + tq;
    tile[r][tc] = src[(size_t)(r0 + r) * srcCols + c0 + tc];
  }
  __syncthreads();
  #pragma unroll
  for (int k = 0; k < 16; ++k) {
    const int cO = k * 4 + tq;
    dst[(size_t)(c0 + cO) * srcRows + r0 + tc] = (__bf16)tile[tc][cO];
  }
}

// ========== m97-structure 128x128 GEMM, BK=32, 4 waves, 4 blocks/CU ==========
// C[M,N] = A[M,K] @ BT[N,K]^T.  EPI: 0=none, 1=+bias[col], 2=+res, 3=phi(col<256)
// R8 diagnosis: the 256^2/128KB-LDS family caps at 1 block/CU (2 waves/SIMD);
// per-MFMA cost ~54 cy vs 4.85 at 8-wave ubench -- occupancy-bound, not
// schedule-bound (R4/R6/R7 schedule edits all ~flat). This 16KB-LDS structure
// runs 4 blocks/CU (16 waves); m103 measured 912 TF for it. Added to R2's
// version of it: (a) LDS XOR swizzle (R2 had 6.55e7 bank conflicts: 16 rows
// x fixed 16B slot = 8-way). Logical slot s of row r stored at phys slot
// s^((r>>1)&3); stage source col and read col carry the same XOR; quarter-wave
// bank aliasing = 2-way (free). (b) XCD slab swizzle (R6: -0.7GB FETCH).
// (c) nontemporal C stores.
template<int EPI>
__global__ __launch_bounds__(256, 4) void gemm128_kernel(
    const bf16_t* __restrict__ A, const bf16_t* __restrict__ BT,
    float* __restrict__ C, const float* __restrict__ extra,
    int N, int K)
{
  __shared__ __align__(16) bf16_t As[128 * 32];
  __shared__ __align__(16) bf16_t Bs[128 * 32];
  // slab swizzle: GY = M/128 = 64 always (M=8192); SLAB = 64/8 = 8 by-rows/XCD.
  const int bid = blockIdx.x;
  const int i = bid >> 3, xcd = bid & 7;
  const int by = xcd * 8 + (i & 7);
  const int bx = i >> 3;
  const int n0 = bx * 128, m0 = by * 128;
  const int t = threadIdx.x;
  const int w = t >> 6, lane = t & 63;
  const int wm = (w >> 1) * 64, wn = (w & 1) * 64;
  const int lr = lane & 15, lq = lane >> 4;
  const int srcc = ((t & 3) ^ ((t >> 3) & 3)) * 8;   // stage src col (pre-swizzled)
  const int rdc  = (lq ^ ((lr >> 1) & 3)) * 8;       // frag read col (swizzled)
  const int srow = t >> 2;                           // stage row within 64-half
  f32x4 acc[4][4] = {};

  for (int k0 = 0; k0 < K; k0 += 32) {
    #pragma unroll
    for (int j = 0; j < 2; ++j) {
      const int r = j * 64 + srow;
      GLD_LDS16(A  + (size_t)(m0 + r) * K + k0 + srcc, As + j * 2048 + w * 512);
      GLD_LDS16(BT + (size_t)(n0 + r) * K + k0 + srcc, Bs + j * 2048 + w * 512);
    }
    asm volatile("s_waitcnt vmcnt(0)" ::: "memory");
    __syncthreads();
    bf16x8 af[4], bfr[4];
    #pragma unroll
    for (int ii = 0; ii < 4; ++ii) {
      af[ii]  = *(const bf16x8*)(As + (wm + ii * 16 + lr) * 32 + rdc);
      bfr[ii] = *(const bf16x8*)(Bs + (wn + ii * 16 + lr) * 32 + rdc);
    }
    #pragma unroll
    for (int mi = 0; mi < 4; ++mi)
      #pragma unroll
      for (int ni = 0; ni < 4; ++ni)
        acc[mi][ni] = __builtin_amdgcn_mfma_f32_16x16x32_bf16(af[mi], bfr[ni], acc[mi][ni], 0, 0, 0);
    __syncthreads();
  }

  // epilogue: C/D layout col=lane&15, row=(lane>>4)*4+reg  [m89-verified]
  // nontemporal: keep the C stream from evicting B out of L2/L3.
  #pragma unroll
  for (int mi = 0; mi < 4; ++mi) {
    #pragma unroll
    for (int r = 0; r < 4; ++r) {
      const int row = m0 + wm + mi * 16 + lq * 4 + r;
      #pragma unroll
      for (int ni = 0; ni < 4; ++ni) {
        const int col = n0 + wn + ni * 16 + lr;
        float v = acc[mi][ni][r];
        if (EPI == 1) v += extra[col];
        if (EPI == 2) v += extra[(size_t)row * N + col];
        if (EPI == 3) { if (col < 256) v = v > 0.f ? v + 1.f : __expf(v); }
        __builtin_nontemporal_store(v, &C[(size_t)row * N + col]);
      }
    }
  }
}

// ---------------- per-chunk G = K^T V and ksum ----------------
__global__ __launch_bounds__(256) void gstate_kernel(
    const float* __restrict__ qkv, float* __restrict__ G, float* __restrict__ KS)
{
  const int g = blockIdx.x;                    // b*128 + c*8 + h
  const int h = g & 7, c = (g >> 3) & 15, b = g >> 7;
  const int t = threadIdx.x;
  const int i = t >> 4, dg = t & 15;           // k-index, 8-col group
  const int srcbase = b * SS + c * CC;
  __shared__ __align__(16) float k_lds[64][16];
  __shared__ __align__(16) float v_lds[64][128];
  float acc[8] = {0,0,0,0,0,0,0,0};
  float ks = 0.f;
  for (int st = 0; st < 4; ++st) {
    __syncthreads();
    { const int sl = t >> 2, i0 = (t & 3) * 4;
      *(float4*)&k_lds[sl][i0] =
        *(const float4*)(qkv + (size_t)(srcbase + st * 64 + sl) * QKVW + 128 + h * 16 + i0); }
    #pragma unroll
    for (int vv = 0; vv < 8; ++vv) {
      const int sl = (t >> 5) + vv * 8, col = (t & 31) * 4;
      *(float4*)&v_lds[sl][col] =
        *(const float4*)(qkv + (size_t)(srcbase + st * 64 + sl) * QKVW + 256 + h * 128 + col);
    }
    __syncthreads();
    for (int sl = 0; sl < 64; ++sl) {
      const float kv = k_lds[sl][i];
      if (dg == 0) ks += kv;
      const float4 va = *(const float4*)&v_lds[sl][dg * 8];
      const float4 vb = *(const float4*)&v_lds[sl][dg * 8 + 4];
      acc[0] = fmaf(kv, va.x, acc[0]); acc[1] = fmaf(kv, va.y, acc[1]);
      acc[2] = fmaf(kv, va.z, acc[2]); acc[3] = fmaf(kv, va.w, acc[3]);
      acc[4] = fmaf(kv, vb.x, acc[4]); acc[5] = fmaf(kv, vb.y, acc[5]);
      acc[6] = fmaf(kv, vb.z, acc[6]); acc[7] = fmaf(kv, vb.w, acc[7]);
    }
  }
  float* gp = G + ((size_t)(b * NC + c) * HH + h) * 2048 + i * 128 + dg * 8;
  *(float4*)gp       = make_float4(acc[0], acc[1], acc[2], acc[3]);
  *(float4*)(gp + 4) = make_float4(acc[4], acc[5], acc[6], acc[7]);
  if (dg == 0) KS[((size_t)(b * NC + c) * HH + h) * 16 + i] = ks;
}

// ---------------- attention: intra (masked) + bypass (prev chunk) + state ----------------
__global__ __launch_bounds__(256) void attn_kernel(
    const float* __restrict__ qkv, const float* __restrict__ Gb,
    const float* __restrict__ KS, bf16_t* __restrict__ outp)
{
  const int bid = blockIdx.x;                   // 512 = b*256 + c*16 + h*2 + dh
  const int dh = bid & 1, h = (bid >> 1) & 7, c = (bid >> 4) & 15, b = bid >> 8;
  const int t = threadIdx.x;
  const int cg = t & 3, rg = t >> 2;            // 16-col group, 4-row group
  const int rowbase = b * SS + c * CC;

  __shared__ __align__(16) float k_lds[64][16];
  __shared__ __align__(16) float v_lds[64][64];
  __shared__ __align__(16) float s_lds[16 * 64];
  __shared__ float z_lds[16];

  float q[4][16];
  #pragma unroll
  for (int rr = 0; rr < 4; ++rr) {
    const float* qp = qkv + (size_t)(rowbase + rg * 4 + rr) * QKVW + h * 16;
    #pragma unroll
    for (int i4 = 0; i4 < 4; ++i4) {
      const float4 qv = *(const float4*)(qp + i4 * 4);
      q[rr][i4*4+0] = qv.x; q[rr][i4*4+1] = qv.y; q[rr][i4*4+2] = qv.z; q[rr][i4*4+3] = qv.w;
    }
  }
  float acc[4][16] = {};
  float den[4] = {0.f, 0.f, 0.f, 0.f};

  for (int ph = 0; ph < 2; ++ph) {
    const int cc = c - ph;                       // ph0: current chunk (masked); ph1: prev chunk
    if (cc < 0) break;
    const int srcbase = b * SS + cc * CC;
    const bool masked = (ph == 0);
    for (int st = 0; st < 4; ++st) {
      __syncthreads();
      { const int sl = t >> 2, i0 = (t & 3) * 4;
        *(float4*)&k_lds[sl][i0] =
          *(const float4*)(qkv + (size_t)(srcbase + st * 64 + sl) * QKVW + 128 + h * 16 + i0); }
      #pragma unroll
      for (int vv = 0; vv < 4; ++vv) {
        const int sl = (t >> 4) + vv * 16, col = (t & 15) * 4;
        *(float4*)&v_lds[sl][col] =
          *(const float4*)(qkv + (size_t)(srcbase + st * 64 + sl) * QKVW + 256 + h * 128 + dh * 64 + col);
      }
      __syncthreads();
      for (int sl = 0; sl < 64; ++sl) {
        float kv[16], vvv[16];
        #pragma unroll
        for (int i4 = 0; i4 < 4; ++i4) {
          const float4 kf = *(const float4*)&k_lds[sl][i4 * 4];
          kv[i4*4+0] = kf.x; kv[i4*4+1] = kf.y; kv[i4*4+2] = kf.z; kv[i4*4+3] = kf.w;
          const float4 vf = *(const float4*)&v_lds[sl][cg * 16 + i4 * 4];
          vvv[i4*4+0] = vf.x; vvv[i4*4+1] = vf.y; vvv[i4*4+2] = vf.z; vvv[i4*4+3] = vf.w;
        }
        const int sidx = st * 64 + sl;
        #pragma unroll
        for (int rr = 0; rr < 4; ++rr) {
          float a = 0.f;
          #pragma unroll
          for (int i = 0; i < 16; ++i) a = fmaf(q[rr][i], kv[i], a);
          if (masked && sidx > rg * 4 + rr) a = 0.f;
          den[rr] += a;                          // intra: q.kcum ; bypass: q.bksum
          #pragma unroll
          for (int e = 0; e < 16; ++e) acc[rr][e] = fmaf(a, vvv[e], acc[rr][e]);
        }
      }
    }
  }

  if (c >= 2) {                                  // long-range state: sum_{j<=c-2} G_j
    float sa0 = 0.f, sa1 = 0.f, sa2 = 0.f, sa3 = 0.f;
    const int si = t >> 4, sc = (t & 15) * 4;
    for (int j = 0; j + 2 <= c; ++j) {
      const float4 gv = *(const float4*)(Gb + ((size_t)(b * NC + j) * HH + h) * 2048
                                            + si * 128 + dh * 64 + sc);
      sa0 += gv.x; sa1 += gv.y; sa2 += gv.z; sa3 += gv.w;
    }
    if (t < 16) {
      float z = 0.f;
      for (int j = 0; j + 2 <= c; ++j) z += KS[((size_t)(b * NC + j) * HH + h) * 16 + t];
      z_lds[t] = z;
    }
    *(float4*)&s_lds[si * 64 + sc] = make_float4(sa0, sa1, sa2, sa3);
    __syncthreads();
    #pragma unroll
    for (int i = 0; i < 16; ++i) {
      float sv[16];
      #pragma unroll
      for (int e4 = 0; e4 < 4; ++e4) {
        const float4 f = *(const float4*)&s_lds[i * 64 + cg * 16 + e4 * 4];
        sv[e4*4+0] = f.x; sv[e4*4+1] = f.y; sv[e4*4+2] = f.z; sv[e4*4+3] = f.w;
      }
      const float zi = z_lds[i];
      #pragma unroll
      for (int rr = 0; rr < 4; ++rr) {
        const float qv = q[rr][i];
        den[rr] = fmaf(qv, zi, den[rr]);
        #pragma unroll
        for (int e = 0; e < 16; ++e) acc[rr][e] = fmaf(qv, sv[e], acc[rr][e]);
      }
    }
  }

  const size_t obase = (size_t)rowbase * DD + h * 128 + dh * 64 + cg * 16;
  #pragma unroll
  for (int rr = 0; rr < 4; ++rr) {
    const float inv = 1.0f / (den[rr] + 1e-6f);
    bf16_t* op = outp + obase + (size_t)(rg * 4 + rr) * DD;
    #pragma unroll
    for (int e4 = 0; e4 < 4; ++e4) {
      bf16x4 bv;
      bv[0] = (__bf16)(acc[rr][e4*4+0] * inv); bv[1] = (__bf16)(acc[rr][e4*4+1] * inv);
      bv[2] = (__bf16)(acc[rr][e4*4+2] * inv); bv[3] = (__bf16)(acc[rr][e4*4+3] * inv);
      *(bf16x4*)(op + e4 * 4) = bv;
    }
  }
}

// ---------------- LayerNorm (eps 1e-5) -> bf16 ----------------
__global__ __launch_bounds__(256) void ln_kernel(
    const float* __restrict__ hbuf, const float* __restrict__ g,
    const float* __restrict__ bta, bf16_t* __restrict__ out)
{
  const int row = blockIdx.x;
  const int t = threadIdx.x;
  const float4 x = ((const float4*)(hbuf + (size_t)row * DD))[t];
  float s  = x.x + x.y + x.z + x.w;
  float s2 = x.x*x.x + x.y*x.y + x.z*x.z + x.w*x.w;
  #pragma unroll
  for (int off = 32; off > 0; off >>= 1) {
    s  += __shfl_down(s,  off, 64);
    s2 += __shfl_down(s2, off, 64);
  }
  __shared__ float ws[8];
  if ((t & 63) == 0) { ws[(t >> 6) * 2] = s; ws[(t >> 6) * 2 + 1] = s2; }
  __syncthreads();
  const float ts  = ws[0] + ws[2] + ws[4] + ws[6];
  const float ts2 = ws[1] + ws[3] + ws[5] + ws[7];
  const float mu  = ts * (1.0f / DD);
  const float var = ts2 * (1.0f / DD) - mu * mu;
  const float inv = rsqrtf(var + 1e-5f);
  const float4 gv = ((const float4*)g)[t];
  const float4 bv = ((const float4*)bta)[t];
  bf16x4 o;
  o[0] = (__bf16)((x.x - mu) * inv * gv.x + bv.x);
  o[1] = (__bf16)((x.y - mu) * inv * gv.y + bv.y);
  o[2] = (__bf16)((x.z - mu) * inv * gv.z + bv.z);
  o[3] = (__bf16)((x.w - mu) * inv * gv.w + bv.w);
  *(bf16x4*)(out + (size_t)row * DD + t * 4) = o;
}

extern "C" void kernel_launch(void* const* d_in, const int* in_sizes, int n_in,
                              void* d_out, int out_size, void* d_ws, size_t ws_size,
                              hipStream_t stream) {
  (void)in_sizes; (void)n_in; (void)out_size; (void)ws_size;
  const int*   x    = (const int*)d_in[0];
  const float* emb  = (const float*)d_in[1];
  const float* Wq   = (const float*)d_in[2];
  const float* Wk   = (const float*)d_in[3];
  const float* Wv   = (const float*)d_in[4];
  const float* Wo   = (const float*)d_in[5];
  const float* ln_g = (const float*)d_in[6];
  const float* ln_b = (const float*)d_in[7];
  const float* outW = (const float*)d_in[8];
  const float* outb = (const float*)d_in[9];
  float* out = (float*)d_out;

  char* ws = (char*)d_ws;
  float*  ctx_f32 = (float*) (ws + 0);            // 33,554,432
  bf16_t* ctx_bf  = (bf16_t*)(ws + 33554432ull);  // 16,777,216
  float*  qkv     = (float*) (ws + 50331648ull);  // 41,943,040 (reused as h f32)
  bf16_t* attn_bf = (bf16_t*)(ws + 92274688ull);  // 16,777,216 (reused as h bf16)
  float*  Gbuf    = (float*) (ws + 109051904ull); //  2,097,152
  float*  KSbuf   = (float*) (ws + 111149056ull); //     16,384
  bf16_t* WqkvT   = (bf16_t*)(ws + 111165440ull); //  2,621,440
  bf16_t* WoT     = (bf16_t*)(ws + 113786880ull); //  2,097,152
  bf16_t* outWT   = (bf16_t*)(ws + 115884032ull); // 65,536,000  (end 181,420,032)
  float*  hbuf    = qkv;
  bf16_t* h_bf    = attn_bf;

  transpose_cvt<<<dim3(2, 16),   256, 0, stream>>>(Wq,   WqkvT,              DD, 128);
  transpose_cvt<<<dim3(2, 16),   256, 0, stream>>>(Wk,   WqkvT + 128 * DD,   DD, 128);
  transpose_cvt<<<dim3(16, 16),  256, 0, stream>>>(Wv,   WqkvT + 256 * DD,   DD, DD);
  transpose_cvt<<<dim3(16, 16),  256, 0, stream>>>(Wo,   WoT,                DD, DD);
  transpose_cvt<<<dim3(500, 16), 256, 0, stream>>>(outW, outWT,              DD, VV);

  ctx_kernel<<<BB * SS, 256, 0, stream>>>(x, emb, ctx_f32, ctx_bf);

  // QKV projection + fused phi on cols<256  (M=8192, N=1280, grid 10*64=640)
  gemm128_kernel<3><<<(QKVW / 128) * (BB * SS / 128), 256, 0, stream>>>(
      ctx_bf, WqkvT, qkv, nullptr, QKVW, DD);

  gstate_kernel<<<BB * NC * HH, 256, 0, stream>>>(qkv, Gbuf, KSbuf);
  attn_kernel<<<BB * NC * HH * 2, 256, 0, stream>>>(qkv, Gbuf, KSbuf, attn_bf);

  // out-proj + residual  (N=1024, grid 8*64=512)
  gemm128_kernel<2><<<(DD / 128) * (BB * SS / 128), 256, 0, stream>>>(
      attn_bf, WoT, hbuf, ctx_f32, DD, DD);

  ln_kernel<<<BB * SS, 256, 0, stream>>>(hbuf, ln_g, ln_b, h_bf);

  // logits + bias  (N=32000, grid 250*64=16000)
  gemm128_kernel<1><<<(VV / 128) * (BB * SS / 128), 256, 0, stream>>>(
      h_bf, outWT, out, outb, VV, DD);
}

// Round 9
// 925.930 us; speedup vs baseline: 1.1962x; 1.1376x over previous
//
#include <hip/hip_runtime.h>
#include <hip/hip_bf16.h>

typedef __bf16 bf16_t;
typedef __bf16 bf16x4 __attribute__((ext_vector_type(4)));
typedef __bf16 bf16x8 __attribute__((ext_vector_type(8)));
typedef float f32x4 __attribute__((ext_vector_type(4)));

#define BB 2
#define SS 4096
#define DD 1024
#define VV 32000
#define HH 8
#define CC 256
#define NC 16

#define GLD_LDS16(gp, lp) __builtin_amdgcn_global_load_lds( \
    (const __attribute__((address_space(1))) void*)(gp),    \
    (__attribute__((address_space(3))) void*)(lp), 16, 0, 0)

// ---------------- ctx: emb gather + 4-tap causal sum ----------------
__global__ __launch_bounds__(256) void ctx_kernel(
    const int* __restrict__ x, const float* __restrict__ emb,
    float* __restrict__ ctx, bf16_t* __restrict__ ctxb)
{
  const int row = blockIdx.x;            // b*SS + s
  const int b = row >> 12, s = row & (SS - 1);
  const int t = threadIdx.x;             // d = t*4
  float4 a = make_float4(0.f, 0.f, 0.f, 0.f);
  #pragma unroll
  for (int o = 0; o < 4; ++o) {
    if (s - o >= 0) {
      const int idx = x[b * SS + s - o];
      const float4 e = *(const float4*)(emb + (size_t)idx * DD + t * 4);
      a.x += e.x; a.y += e.y; a.z += e.z; a.w += e.w;
    }
  }
  *(float4*)(ctx + (size_t)row * DD + t * 4) = a;
  bf16x4 bv;
  bv[0] = (__bf16)a.x; bv[1] = (__bf16)a.y; bv[2] = (__bf16)a.z; bv[3] = (__bf16)a.w;
  *(bf16x4*)(ctxb + (size_t)row * DD + t * 4) = bv;
}

// ---------------- transpose + f32->bf16: dst[c][r] = src[r][c] ----------------
__global__ __launch_bounds__(256) void transpose_cvt(
    const float* __restrict__ src, bf16_t* __restrict__ dst,
    int srcRows, int srcCols)
{
  __shared__ __align__(16) float tile[64][65];
  const int c0 = blockIdx.x * 64, r0 = blockIdx.y * 64;
  const int tc = threadIdx.x & 63, tq = threadIdx.x >> 6;
  #pragma unroll
  for (int k = 0; k < 16; ++k) {
    const int r = k * 4 + tq;
    tile[r][tc] = src[(size_t)(r0 + r) * srcCols + c0 + tc];
  }
  __syncthreads();
  #pragma unroll
  for (int k = 0; k < 16; ++k) {
    const int cO = k * 4 + tq;
    dst[(size_t)(c0 + cO) * srcRows + r0 + tc] = (__bf16)tile[tc][cO];
  }
}

// ========== m97-structure 128x128 GEMM, BK=32, 4 waves, ~4 blocks/CU ==========
// EPI: 1=+bias[col] (logits), 2=+res (Wo), 3=QKV epilogue: q/k phi->bf16 to
// qb/kb, v -> bf16 TRANSPOSED vT[(b*8+h)*128+dv][s] (pack-4 along s).
template<int EPI>
__global__ __launch_bounds__(256, 4) void gemm128_kernel(
    const bf16_t* __restrict__ A, const bf16_t* __restrict__ BT,
    float* __restrict__ C, const float* __restrict__ extra,
    bf16_t* __restrict__ qb, bf16_t* __restrict__ kbx, bf16_t* __restrict__ vtb,
    int N, int K)
{
  __shared__ __align__(16) bf16_t As[128 * 32];
  __shared__ __align__(16) bf16_t Bs[128 * 32];
  const int bid = blockIdx.x;
  const int i = bid >> 3, xcd = bid & 7;
  const int by = xcd * 8 + (i & 7);          // GY = M/128 = 64 always
  const int bx = i >> 3;
  const int n0 = bx * 128, m0 = by * 128;
  const int t = threadIdx.x;
  const int w = t >> 6, lane = t & 63;
  const int wm = (w >> 1) * 64, wn = (w & 1) * 64;
  const int lr = lane & 15, lq = lane >> 4;
  const int srcc = ((t & 3) ^ ((t >> 3) & 3)) * 8;   // stage src col (pre-swizzled)
  const int rdc  = (lq ^ ((lr >> 1) & 3)) * 8;       // frag read col (swizzled)
  const int srow = t >> 2;
  f32x4 acc[4][4] = {};

  for (int k0 = 0; k0 < K; k0 += 32) {
    #pragma unroll
    for (int j = 0; j < 2; ++j) {
      const int r = j * 64 + srow;
      GLD_LDS16(A  + (size_t)(m0 + r) * K + k0 + srcc, As + j * 2048 + w * 512);
      GLD_LDS16(BT + (size_t)(n0 + r) * K + k0 + srcc, Bs + j * 2048 + w * 512);
    }
    asm volatile("s_waitcnt vmcnt(0)" ::: "memory");
    __syncthreads();
    bf16x8 af[4], bfr[4];
    #pragma unroll
    for (int ii = 0; ii < 4; ++ii) {
      af[ii]  = *(const bf16x8*)(As + (wm + ii * 16 + lr) * 32 + rdc);
      bfr[ii] = *(const bf16x8*)(Bs + (wn + ii * 16 + lr) * 32 + rdc);
    }
    #pragma unroll
    for (int mi = 0; mi < 4; ++mi)
      #pragma unroll
      for (int ni = 0; ni < 4; ++ni)
        acc[mi][ni] = __builtin_amdgcn_mfma_f32_16x16x32_bf16(af[mi], bfr[ni], acc[mi][ni], 0, 0, 0);
    __syncthreads();
  }

  // C/D layout: col=lane&15, row=(lane>>4)*4+reg  [m89-verified]
  if (EPI == 3) {
    #pragma unroll
    for (int mi = 0; mi < 4; ++mi) {
      const int row0 = m0 + wm + mi * 16 + lq * 4;
      #pragma unroll
      for (int ni = 0; ni < 4; ++ni) {
        const int col = n0 + wn + ni * 16 + lr;
        if (col < 256) {                       // q | k : phi -> bf16 (block-uniform)
          #pragma unroll
          for (int r = 0; r < 4; ++r) {
            float v = acc[mi][ni][r];
            v = v > 0.f ? v + 1.f : __expf(v);
            if (col < 128) qb [(size_t)(row0 + r) * 128 + col      ] = (__bf16)v;
            else           kbx[(size_t)(row0 + r) * 128 + col - 128] = (__bf16)v;
          }
        } else {                               // v -> transposed bf16
          const int vcol = col - 256;
          const int hh = vcol >> 7, dv = vcol & 127;
          const int bb = row0 >> 12, s0 = row0 & (SS - 1);
          bf16x4 pv;
          #pragma unroll
          for (int r = 0; r < 4; ++r) pv[r] = (__bf16)acc[mi][ni][r];
          *(bf16x4*)(vtb + ((size_t)((bb * HH + hh) * 128 + dv)) * SS + s0) = pv;
        }
      }
    }
    return;
  }
  #pragma unroll
  for (int mi = 0; mi < 4; ++mi) {
    #pragma unroll
    for (int r = 0; r < 4; ++r) {
      const int row = m0 + wm + mi * 16 + lq * 4 + r;
      #pragma unroll
      for (int ni = 0; ni < 4; ++ni) {
        const int col = n0 + wn + ni * 16 + lr;
        float v = acc[mi][ni][r];
        if (EPI == 1) v += extra[col];
        if (EPI == 2) v += extra[(size_t)row * N + col];
        __builtin_nontemporal_store(v, &C[(size_t)row * N + col]);
      }
    }
  }
}

// ---------------- per-chunk G = K^T V (MFMA) and ksum ----------------
__global__ __launch_bounds__(64) void gstate_kernel(
    const bf16_t* __restrict__ kb, const bf16_t* __restrict__ vT,
    float* __restrict__ G, float* __restrict__ KS)
{
  const int bid = blockIdx.x;                  // b*128 + c*8 + h
  const int h = bid & 7, c = (bid >> 3) & 15, b = bid >> 7;
  const int lane = threadIdx.x;
  const int lr = lane & 15, lq = lane >> 4;
  __shared__ __align__(16) bf16_t ktl[16][264]; // k transposed: [i][s]
  for (int ss = 0; ss < 4; ++ss) {
    const int s = ss * 64 + lane;
    const bf16_t* src = kb + (size_t)(b * SS + c * CC + s) * 128 + h * 16;
    const bf16x8 v0 = *(const bf16x8*)src;
    const bf16x8 v1 = *(const bf16x8*)(src + 8);
    #pragma unroll
    for (int ii = 0; ii < 8; ++ii) { ktl[ii][s] = v0[ii]; ktl[8 + ii][s] = v1[ii]; }
  }
  __syncthreads();
  if (lane < 16) {
    float ks = 0.f;
    for (int s = 0; s < 256; ++s) ks += (float)ktl[lane][s];
    KS[((size_t)((b * NC + c) * HH + h)) * 16 + lane] = ks;
  }
  bf16x8 af[8];
  #pragma unroll
  for (int sk = 0; sk < 8; ++sk)
    af[sk] = *(const bf16x8*)&ktl[lr][sk * 32 + lq * 8];
  float* gout = G + ((size_t)((b * NC + c) * HH + h)) * 2048;
  #pragma unroll
  for (int nf = 0; nf < 8; ++nf) {
    f32x4 acc = {0.f, 0.f, 0.f, 0.f};
    #pragma unroll
    for (int sk = 0; sk < 8; ++sk) {
      const bf16x8 vb = *(const bf16x8*)(vT +
          ((size_t)((b * HH + h) * 128 + nf * 16 + lr)) * SS + c * CC + sk * 32 + lq * 8);
      acc = __builtin_amdgcn_mfma_f32_16x16x32_bf16(af[sk], vb, acc, 0, 0, 0);
    }
    #pragma unroll
    for (int r = 0; r < 4; ++r)
      gout[(size_t)(lq * 4 + r) * 128 + nf * 16 + lr] = acc[r];
  }
}

// ---------------- MFMA attention: intra(masked) + bypass + state ----------------
// Block = (b,c,h), 512 thr / 8 waves; wave owns 32 q-rows. Keys 0..255 = prev
// chunk (bypass), 256..511 = current (causal-masked). K-dim 16 zero-padded to
// 32 via lane-select (lq>=2 -> 0). P: per-wave LDS, same-wave write->read (DS
// in-order, no barrier). den = row-sum of masked att (+ q.z state term).
__global__ __launch_bounds__(512, 2) void attn_kernel(
    const bf16_t* __restrict__ qb, const bf16_t* __restrict__ kb,
    const bf16_t* __restrict__ vT, const float* __restrict__ Gb,
    const float* __restrict__ KS, bf16_t* __restrict__ outp)
{
  const int bid = blockIdx.x;                  // b*128 + c*8 + h
  const int h = bid & 7, c = (bid >> 3) & 15, b = bid >> 7;
  const int t = threadIdx.x;
  const int w = t >> 6, lane = t & 63;
  const int lr = lane & 15, lq = lane >> 4;
  const int rowbase = b * SS + c * CC;

  __shared__ __align__(16) bf16_t q_lds[256][24];
  __shared__ __align__(16) bf16_t k_lds[512][24];
  __shared__ __align__(16) bf16_t vt_lds[128][72];
  __shared__ __align__(16) bf16_t p_lds[8][32][72];
  __shared__ float s_f32[16][128];
  __shared__ float z_lds[16];
  __shared__ float dstate[256];

  if (t < 256) {                               // stage q rows (bf16, 32B each)
    const bf16_t* src = qb + (size_t)(rowbase + t) * 128 + h * 16;
    *(uint4*)&q_lds[t][0] = *(const uint4*)src;
    *(uint4*)&q_lds[t][8] = *(const uint4*)(src + 8);
  }
  {                                            // stage k rows: prev | cur
    if (t < 256 && c == 0) {
      const uint4 z = {0u, 0u, 0u, 0u};
      *(uint4*)&k_lds[t][0] = z; *(uint4*)&k_lds[t][8] = z;
    } else {
      const int sg = (t < 256) ? (c - 1) * CC + t : c * CC + (t - 256);
      const bf16_t* src = kb + (size_t)(b * SS + sg) * 128 + h * 16;
      *(uint4*)&k_lds[t][0] = *(const uint4*)src;
      *(uint4*)&k_lds[t][8] = *(const uint4*)(src + 8);
    }
  }
  if (t < 16) {                                // z[i] = sum_{j<=c-2} ksum_j[i]
    float z = 0.f;
    for (int j = 0; j + 2 <= c; ++j) z += KS[((size_t)((b * NC + j) * HH + h)) * 16 + t];
    z_lds[t] = z;
  }
  if (c >= 2) {                                // S = sum_{j<=c-2} G_j
    for (int idx = t; idx < 2048; idx += 512) {
      float sv = 0.f;
      for (int j = 0; j + 2 <= c; ++j)
        sv += Gb[((size_t)((b * NC + j) * HH + h)) * 2048 + idx];
      ((float*)s_f32)[idx] = sv;
    }
  }
  __syncthreads();
  if (t < 256) {                               // dstate[row] = q[row].z
    float d = 0.f;
    #pragma unroll
    for (int ii = 0; ii < 16; ++ii) d += (float)q_lds[t][ii] * z_lds[ii];
    dstate[t] = d;
  }

  const int wrow = w * 32;
  bf16x8 qf[2];
  #pragma unroll
  for (int mi = 0; mi < 2; ++mi) {
    bf16x8 v = {};
    if (lq < 2) v = *(const bf16x8*)&q_lds[wrow + mi * 16 + lr][lq * 8];
    qf[mi] = v;
  }
  f32x4 acc[2][8] = {};
  float den_l[2][4] = {};
  const int nc0 = (c == 0) ? 4 : 0;

  for (int nc = nc0; nc < 8; ++nc) {
    __syncthreads();                           // vt_lds reuse safe
    {                                          // stage V^T chunk [128 dv][64 keys]
      const int dv = t >> 2, kk = (t & 3) * 16;
      const int key0 = nc * 64;
      const int sg = (key0 < 256) ? (c - 1) * CC + key0 : c * CC + key0 - 256;
      const bf16_t* src = vT + ((size_t)((b * HH + h) * 128 + dv)) * SS + sg + kk;
      *(uint4*)&vt_lds[dv][kk]     = *(const uint4*)src;
      *(uint4*)&vt_lds[dv][kk + 8] = *(const uint4*)(src + 8);
    }
    __syncthreads();
    f32x4 attf[2][4];
    #pragma unroll
    for (int nf = 0; nf < 4; ++nf) {
      bf16x8 kv = {};
      if (lq < 2) kv = *(const bf16x8*)&k_lds[nc * 64 + nf * 16 + lr][lq * 8];
      #pragma unroll
      for (int mi = 0; mi < 2; ++mi) {
        const f32x4 zero = {0.f, 0.f, 0.f, 0.f};
        attf[mi][nf] = __builtin_amdgcn_mfma_f32_16x16x32_bf16(qf[mi], kv, zero, 0, 0, 0);
      }
    }
    #pragma unroll
    for (int mi = 0; mi < 2; ++mi)
      #pragma unroll
      for (int nf = 0; nf < 4; ++nf)
        #pragma unroll
        for (int r = 0; r < 4; ++r) {
          const int row_l = wrow + mi * 16 + lq * 4 + r;
          const int key_l = nc * 64 + nf * 16 + lr;
          float a = attf[mi][nf][r];
          if (key_l >= 256 && key_l - 256 > row_l) a = 0.f;
          den_l[mi][r] += a;
          p_lds[w][mi * 16 + lq * 4 + r][nf * 16 + lr] = (__bf16)a;
        }
    #pragma unroll
    for (int ks = 0; ks < 2; ++ks) {
      bf16x8 pa[2];
      #pragma unroll
      for (int mi = 0; mi < 2; ++mi)
        pa[mi] = *(const bf16x8*)&p_lds[w][mi * 16 + lr][ks * 32 + lq * 8];
      #pragma unroll
      for (int nf = 0; nf < 8; ++nf) {
        const bf16x8 vb = *(const bf16x8*)&vt_lds[nf * 16 + lr][ks * 32 + lq * 8];
        #pragma unroll
        for (int mi = 0; mi < 2; ++mi)
          acc[mi][nf] = __builtin_amdgcn_mfma_f32_16x16x32_bf16(pa[mi], vb, acc[mi][nf], 0, 0, 0);
      }
    }
  }

  if (c >= 2) {                                // state numerator: acc += q.S
    #pragma unroll
    for (int mi = 0; mi < 2; ++mi)
      for (int r = 0; r < 4; ++r) {
        const int row_l = wrow + mi * 16 + lq * 4 + r;
        float qrow[16];
        #pragma unroll
        for (int ii = 0; ii < 16; ++ii) qrow[ii] = (float)q_lds[row_l][ii];
        #pragma unroll
        for (int nf = 0; nf < 8; ++nf) {
          float sacc = 0.f;
          #pragma unroll
          for (int ii = 0; ii < 16; ++ii) sacc += qrow[ii] * s_f32[ii][nf * 16 + lr];
          acc[mi][nf][r] += sacc;
        }
      }
  }
  #pragma unroll
  for (int mi = 0; mi < 2; ++mi)
    #pragma unroll
    for (int r = 0; r < 4; ++r) {
      float d = den_l[mi][r];
      d += __shfl_xor(d, 1, 64); d += __shfl_xor(d, 2, 64);
      d += __shfl_xor(d, 4, 64); d += __shfl_xor(d, 8, 64);
      const int row_l = wrow + mi * 16 + lq * 4 + r;
      den_l[mi][r] = 1.0f / (d + dstate[row_l] + 1e-6f);
    }
  #pragma unroll
  for (int mi = 0; mi < 2; ++mi)
    #pragma unroll
    for (int r = 0; r < 4; ++r) {
      const size_t row_g = rowbase + wrow + mi * 16 + lq * 4 + r;
      const float inv = den_l[mi][r];
      #pragma unroll
      for (int nf = 0; nf < 8; ++nf)
        outp[row_g * DD + h * 128 + nf * 16 + lr] = (__bf16)(acc[mi][nf][r] * inv);
    }
}

// ---------------- LayerNorm (eps 1e-5) -> bf16 ----------------
__global__ __launch_bounds__(256) void ln_kernel(
    const float* __restrict__ hbuf, const float* __restrict__ g,
    const float* __restrict__ bta, bf16_t* __restrict__ out)
{
  const int row = blockIdx.x;
  const int t = threadIdx.x;
  const float4 x = ((const float4*)(hbuf + (size_t)row * DD))[t];
  float s  = x.x + x.y + x.z + x.w;
  float s2 = x.x*x.x + x.y*x.y + x.z*x.z + x.w*x.w;
  #pragma unroll
  for (int off = 32; off > 0; off >>= 1) {
    s  += __shfl_down(s,  off, 64);
    s2 += __shfl_down(s2, off, 64);
  }
  __shared__ float ws[8];
  if ((t & 63) == 0) { ws[(t >> 6) * 2] = s; ws[(t >> 6) * 2 + 1] = s2; }
  __syncthreads();
  const float ts  = ws[0] + ws[2] + ws[4] + ws[6];
  const float ts2 = ws[1] + ws[3] + ws[5] + ws[7];
  const float mu  = ts * (1.0f / DD);
  const float var = ts2 * (1.0f / DD) - mu * mu;
  const float inv = rsqrtf(var + 1e-5f);
  const float4 gv = ((const float4*)g)[t];
  const float4 bv = ((const float4*)bta)[t];
  bf16x4 o;
  o[0] = (__bf16)((x.x - mu) * inv * gv.x + bv.x);
  o[1] = (__bf16)((x.y - mu) * inv * gv.y + bv.y);
  o[2] = (__bf16)((x.z - mu) * inv * gv.z + bv.z);
  o[3] = (__bf16)((x.w - mu) * inv * gv.w + bv.w);
  *(bf16x4*)(out + (size_t)row * DD + t * 4) = o;
}

extern "C" void kernel_launch(void* const* d_in, const int* in_sizes, int n_in,
                              void* d_out, int out_size, void* d_ws, size_t ws_size,
                              hipStream_t stream) {
  (void)in_sizes; (void)n_in; (void)out_size; (void)ws_size;
  const int*   x    = (const int*)d_in[0];
  const float* emb  = (const float*)d_in[1];
  const float* Wq   = (const float*)d_in[2];
  const float* Wk   = (const float*)d_in[3];
  const float* Wv   = (const float*)d_in[4];
  const float* Wo   = (const float*)d_in[5];
  const float* ln_g = (const float*)d_in[6];
  const float* ln_b = (const float*)d_in[7];
  const float* outW = (const float*)d_in[8];
  const float* outb = (const float*)d_in[9];
  float* out = (float*)d_out;

  char* ws = (char*)d_ws;
  float*  ctx_f32 = (float*) (ws + 0);             // 33,554,432 (live till Wo)
  bf16_t* ctx_bf  = (bf16_t*)(ws + 33554432ull);   // 16,777,216 (dead after QKV)
  bf16_t* qbuf    = (bf16_t*)(ws + 50331648ull);   //  2,097,152
  bf16_t* kbuf    = (bf16_t*)(ws + 52428800ull);   //  2,097,152
  bf16_t* vTbuf   = (bf16_t*)(ws + 54525952ull);   // 16,777,216 (dead after attn)
  bf16_t* attn_bf = (bf16_t*)(ws + 71303168ull);   // 16,777,216 (reused as h_bf)
  float*  Gbuf    = (float*) (ws + 88080384ull);   //  2,097,152
  float*  KSbuf   = (float*) (ws + 90177536ull);   //     16,384
  bf16_t* WqkvT   = (bf16_t*)(ws + 90193920ull);   //  2,621,440
  bf16_t* WoT     = (bf16_t*)(ws + 92815360ull);   //  2,097,152
  bf16_t* outWT   = (bf16_t*)(ws + 94912512ull);   // 65,536,000 (end 160,448,512)
  float*  hbuf    = (float*) (ws + 33554432ull);   // 33,554,432 overlay (ctx_bf..vT dead)
  bf16_t* h_bf    = attn_bf;

  transpose_cvt<<<dim3(2, 16),   256, 0, stream>>>(Wq,   WqkvT,             DD, 128);
  transpose_cvt<<<dim3(2, 16),   256, 0, stream>>>(Wk,   WqkvT + 128 * DD,  DD, 128);
  transpose_cvt<<<dim3(16, 16),  256, 0, stream>>>(Wv,   WqkvT + 256 * DD,  DD, DD);
  transpose_cvt<<<dim3(16, 16),  256, 0, stream>>>(Wo,   WoT,               DD, DD);
  transpose_cvt<<<dim3(500, 16), 256, 0, stream>>>(outW, outWT,             DD, VV);

  ctx_kernel<<<BB * SS, 256, 0, stream>>>(x, emb, ctx_f32, ctx_bf);

  // QKV projection, epilogue: phi(q,k)->bf16 qb/kb, v->bf16 transposed vT
  gemm128_kernel<3><<<(1280 / 128) * (BB * SS / 128), 256, 0, stream>>>(
      ctx_bf, WqkvT, nullptr, nullptr, qbuf, kbuf, vTbuf, 1280, DD);

  gstate_kernel<<<BB * NC * HH, 64, 0, stream>>>(kbuf, vTbuf, Gbuf, KSbuf);
  attn_kernel<<<BB * NC * HH, 512, 0, stream>>>(qbuf, kbuf, vTbuf, Gbuf, KSbuf, attn_bf);

  // out-proj + residual
  gemm128_kernel<2><<<(DD / 128) * (BB * SS / 128), 256, 0, stream>>>(
      attn_bf, WoT, hbuf, ctx_f32, nullptr, nullptr, nullptr, DD, DD);

  ln_kernel<<<BB * SS, 256, 0, stream>>>(hbuf, ln_g, ln_b, h_bf);

  // logits + bias
  gemm128_kernel<1><<<(VV / 128) * (BB * SS / 128), 256, 0, stream>>>(
      h_bf, outWT, out, outb, nullptr, nullptr, nullptr, VV, DD);
}

// Round 10
// 817.271 us; speedup vs baseline: 1.3552x; 1.1330x over previous
//
#include <hip/hip_runtime.h>
#include <hip/hip_bf16.h>

typedef __bf16 bf16_t;
typedef __bf16 bf16x4 __attribute__((ext_vector_type(4)));
typedef __bf16 bf16x8 __attribute__((ext_vector_type(8)));
typedef float f32x4 __attribute__((ext_vector_type(4)));

#define BB 2
#define SS 4096
#define DD 1024
#define VV 32000
#define HH 8
#define CC 256
#define NC 16

#define GLD_LDS16(gp, lp) __builtin_amdgcn_global_load_lds( \
    (const __attribute__((address_space(1))) void*)(gp),    \
    (__attribute__((address_space(3))) void*)(lp), 16, 0, 0)

// ---------------- ctx: emb gather + 4-tap causal sum ----------------
__global__ __launch_bounds__(256) void ctx_kernel(
    const int* __restrict__ x, const float* __restrict__ emb,
    float* __restrict__ ctx, bf16_t* __restrict__ ctxb)
{
  const int row = blockIdx.x;            // b*SS + s
  const int b = row >> 12, s = row & (SS - 1);
  const int t = threadIdx.x;             // d = t*4
  float4 a = make_float4(0.f, 0.f, 0.f, 0.f);
  #pragma unroll
  for (int o = 0; o < 4; ++o) {
    if (s - o >= 0) {
      const int idx = x[b * SS + s - o];
      const float4 e = *(const float4*)(emb + (size_t)idx * DD + t * 4);
      a.x += e.x; a.y += e.y; a.z += e.z; a.w += e.w;
    }
  }
  *(float4*)(ctx + (size_t)row * DD + t * 4) = a;
  bf16x4 bv;
  bv[0] = (__bf16)a.x; bv[1] = (__bf16)a.y; bv[2] = (__bf16)a.z; bv[3] = (__bf16)a.w;
  *(bf16x4*)(ctxb + (size_t)row * DD + t * 4) = bv;
}

// ---------------- transpose + f32->bf16: dst[c][r] = src[r][c] ----------------
__global__ __launch_bounds__(256) void transpose_cvt(
    const float* __restrict__ src, bf16_t* __restrict__ dst,
    int srcRows, int srcCols)
{
  __shared__ __align__(16) float tile[64][65];
  const int c0 = blockIdx.x * 64, r0 = blockIdx.y * 64;
  const int tc = threadIdx.x & 63, tq = threadIdx.x >> 6;
  #pragma unroll
  for (int k = 0; k < 16; ++k) {
    const int r = k * 4 + tq;
    tile[r][tc] = src[(size_t)(r0 + r) * srcCols + c0 + tc];
  }
  __syncthreads();
  #pragma unroll
  for (int k = 0; k < 16; ++k) {
    const int cO = k * 4 + tq;
    dst[(size_t)(c0 + cO) * srcRows + r0 + tc] = (__bf16)tile[tc][cO];
  }
}

// ========== m97-structure 128x128 GEMM, BK=64, 4 waves, 4 blocks/CU ==========
// R10: BK 32->64 (single change). Per K-tile/wave: 32 MFMA between barriers
// (2x compute per vmcnt(0)+barrier convoy), 16 ds_read_b128, 8 gld_lds. LDS
// 32KB keeps 4 blocks/CU (m132's regression was the 64KB/2-block cliff).
// Swizzle for [128][64] rows=128B: 16B-slot s of row r at s^(r&7); stage
// source pre-XORed (linear gld_lds dest, rule #21); reads 2 lanes/slot=free.
// EPI: 1=+bias[col] (logits), 2=+res (Wo), 3=QKV epilogue: q/k phi->bf16,
// v -> bf16 TRANSPOSED vT[(b*8+h)*128+dv][s].
template<int EPI>
__global__ __launch_bounds__(256, 4) void gemm128_kernel(
    const bf16_t* __restrict__ A, const bf16_t* __restrict__ BT,
    float* __restrict__ C, const float* __restrict__ extra,
    bf16_t* __restrict__ qb, bf16_t* __restrict__ kbx, bf16_t* __restrict__ vtb,
    int N, int K)
{
  __shared__ __align__(16) bf16_t As[128 * 64];
  __shared__ __align__(16) bf16_t Bs[128 * 64];
  const int bid = blockIdx.x;
  const int i = bid >> 3, xcd = bid & 7;
  const int by = xcd * 8 + (i & 7);          // GY = M/128 = 64 always
  const int bx = i >> 3;
  const int n0 = bx * 128, m0 = by * 128;
  const int t = threadIdx.x;
  const int w = t >> 6, lane = t & 63;
  const int wm = (w >> 1) * 64, wn = (w & 1) * 64;
  const int lr = lane & 15, lq = lane >> 4;
  f32x4 acc[4][4] = {};

  for (int k0 = 0; k0 < K; k0 += 64) {
    #pragma unroll
    for (int j = 0; j < 4; ++j) {
      const int idx = j * 256 + t;
      const int r = idx >> 3;
      const int sc = ((idx & 7) ^ (r & 7)) * 8;      // pre-swizzled src col
      GLD_LDS16(A  + (size_t)(m0 + r) * K + k0 + sc, As + (size_t)idx * 8);
      GLD_LDS16(BT + (size_t)(n0 + r) * K + k0 + sc, Bs + (size_t)idx * 8);
    }
    asm volatile("s_waitcnt vmcnt(0)" ::: "memory");
    __syncthreads();
    bf16x8 af[4][2], bfr[4][2];
    #pragma unroll
    for (int ii = 0; ii < 4; ++ii) {
      const int ra = wm + ii * 16 + lr;
      const int rb = wn + ii * 16 + lr;
      #pragma unroll
      for (int ks = 0; ks < 2; ++ks) {
        const int col = ((ks * 4 + lq) ^ (lr & 7)) * 8;   // swizzled read col
        af[ii][ks]  = *(const bf16x8*)(As + ra * 64 + col);
        bfr[ii][ks] = *(const bf16x8*)(Bs + rb * 64 + col);
      }
    }
    #pragma unroll
    for (int mi = 0; mi < 4; ++mi)
      #pragma unroll
      for (int ni = 0; ni < 4; ++ni) {
        acc[mi][ni] = __builtin_amdgcn_mfma_f32_16x16x32_bf16(af[mi][0], bfr[ni][0], acc[mi][ni], 0, 0, 0);
        acc[mi][ni] = __builtin_amdgcn_mfma_f32_16x16x32_bf16(af[mi][1], bfr[ni][1], acc[mi][ni], 0, 0, 0);
      }
    __syncthreads();
  }

  // C/D layout: col=lane&15, row=(lane>>4)*4+reg  [m89-verified]
  if (EPI == 3) {
    #pragma unroll
    for (int mi = 0; mi < 4; ++mi) {
      const int row0 = m0 + wm + mi * 16 + lq * 4;
      #pragma unroll
      for (int ni = 0; ni < 4; ++ni) {
        const int col = n0 + wn + ni * 16 + lr;
        if (col < 256) {                       // q | k : phi -> bf16 (block-uniform)
          #pragma unroll
          for (int r = 0; r < 4; ++r) {
            float v = acc[mi][ni][r];
            v = v > 0.f ? v + 1.f : __expf(v);
            if (col < 128) qb [(size_t)(row0 + r) * 128 + col      ] = (__bf16)v;
            else           kbx[(size_t)(row0 + r) * 128 + col - 128] = (__bf16)v;
          }
        } else {                               // v -> transposed bf16
          const int vcol = col - 256;
          const int hh = vcol >> 7, dv = vcol & 127;
          const int bb = row0 >> 12, s0 = row0 & (SS - 1);
          bf16x4 pv;
          #pragma unroll
          for (int r = 0; r < 4; ++r) pv[r] = (__bf16)acc[mi][ni][r];
          *(bf16x4*)(vtb + ((size_t)((bb * HH + hh) * 128 + dv)) * SS + s0) = pv;
        }
      }
    }
    return;
  }
  #pragma unroll
  for (int mi = 0; mi < 4; ++mi) {
    #pragma unroll
    for (int r = 0; r < 4; ++r) {
      const int row = m0 + wm + mi * 16 + lq * 4 + r;
      #pragma unroll
      for (int ni = 0; ni < 4; ++ni) {
        const int col = n0 + wn + ni * 16 + lr;
        float v = acc[mi][ni][r];
        if (EPI == 1) v += extra[col];
        if (EPI == 2) v += extra[(size_t)row * N + col];
        __builtin_nontemporal_store(v, &C[(size_t)row * N + col]);
      }
    }
  }
}

// ---------------- per-chunk G = K^T V (MFMA) and ksum ----------------
__global__ __launch_bounds__(64) void gstate_kernel(
    const bf16_t* __restrict__ kb, const bf16_t* __restrict__ vT,
    float* __restrict__ G, float* __restrict__ KS)
{
  const int bid = blockIdx.x;                  // b*128 + c*8 + h
  const int h = bid & 7, c = (bid >> 3) & 15, b = bid >> 7;
  const int lane = threadIdx.x;
  const int lr = lane & 15, lq = lane >> 4;
  __shared__ __align__(16) bf16_t ktl[16][264]; // k transposed: [i][s]
  for (int ss = 0; ss < 4; ++ss) {
    const int s = ss * 64 + lane;
    const bf16_t* src = kb + (size_t)(b * SS + c * CC + s) * 128 + h * 16;
    const bf16x8 v0 = *(const bf16x8*)src;
    const bf16x8 v1 = *(const bf16x8*)(src + 8);
    #pragma unroll
    for (int ii = 0; ii < 8; ++ii) { ktl[ii][s] = v0[ii]; ktl[8 + ii][s] = v1[ii]; }
  }
  __syncthreads();
  if (lane < 16) {
    float ks = 0.f;
    for (int s = 0; s < 256; ++s) ks += (float)ktl[lane][s];
    KS[((size_t)((b * NC + c) * HH + h)) * 16 + lane] = ks;
  }
  bf16x8 af[8];
  #pragma unroll
  for (int sk = 0; sk < 8; ++sk)
    af[sk] = *(const bf16x8*)&ktl[lr][sk * 32 + lq * 8];
  float* gout = G + ((size_t)((b * NC + c) * HH + h)) * 2048;
  #pragma unroll
  for (int nf = 0; nf < 8; ++nf) {
    f32x4 acc = {0.f, 0.f, 0.f, 0.f};
    #pragma unroll
    for (int sk = 0; sk < 8; ++sk) {
      const bf16x8 vb = *(const bf16x8*)(vT +
          ((size_t)((b * HH + h) * 128 + nf * 16 + lr)) * SS + c * CC + sk * 32 + lq * 8);
      acc = __builtin_amdgcn_mfma_f32_16x16x32_bf16(af[sk], vb, acc, 0, 0, 0);
    }
    #pragma unroll
    for (int r = 0; r < 4; ++r)
      gout[(size_t)(lq * 4 + r) * 128 + nf * 16 + lr] = acc[r];
  }
}

// ---------------- MFMA attention: intra(masked) + bypass + state ----------------
__global__ __launch_bounds__(512, 2) void attn_kernel(
    const bf16_t* __restrict__ qb, const bf16_t* __restrict__ kb,
    const bf16_t* __restrict__ vT, const float* __restrict__ Gb,
    const float* __restrict__ KS, bf16_t* __restrict__ outp)
{
  const int bid = blockIdx.x;                  // b*128 + c*8 + h
  const int h = bid & 7, c = (bid >> 3) & 15, b = bid >> 7;
  const int t = threadIdx.x;
  const int w = t >> 6, lane = t & 63;
  const int lr = lane & 15, lq = lane >> 4;
  const int rowbase = b * SS + c * CC;

  __shared__ __align__(16) bf16_t q_lds[256][24];
  __shared__ __align__(16) bf16_t k_lds[512][24];
  __shared__ __align__(16) bf16_t vt_lds[128][72];
  __shared__ __align__(16) bf16_t p_lds[8][32][72];
  __shared__ float s_f32[16][128];
  __shared__ float z_lds[16];
  __shared__ float dstate[256];

  if (t < 256) {                               // stage q rows (bf16, 32B each)
    const bf16_t* src = qb + (size_t)(rowbase + t) * 128 + h * 16;
    *(uint4*)&q_lds[t][0] = *(const uint4*)src;
    *(uint4*)&q_lds[t][8] = *(const uint4*)(src + 8);
  }
  {                                            // stage k rows: prev | cur
    if (t < 256 && c == 0) {
      const uint4 z = {0u, 0u, 0u, 0u};
      *(uint4*)&k_lds[t][0] = z; *(uint4*)&k_lds[t][8] = z;
    } else {
      const int sg = (t < 256) ? (c - 1) * CC + t : c * CC + (t - 256);
      const bf16_t* src = kb + (size_t)(b * SS + sg) * 128 + h * 16;
      *(uint4*)&k_lds[t][0] = *(const uint4*)src;
      *(uint4*)&k_lds[t][8] = *(const uint4*)(src + 8);
    }
  }
  if (t < 16) {                                // z[i] = sum_{j<=c-2} ksum_j[i]
    float z = 0.f;
    for (int j = 0; j + 2 <= c; ++j) z += KS[((size_t)((b * NC + j) * HH + h)) * 16 + t];
    z_lds[t] = z;
  }
  if (c >= 2) {                                // S = sum_{j<=c-2} G_j
    for (int idx = t; idx < 2048; idx += 512) {
      float sv = 0.f;
      for (int j = 0; j + 2 <= c; ++j)
        sv += Gb[((size_t)((b * NC + j) * HH + h)) * 2048 + idx];
      ((float*)s_f32)[idx] = sv;
    }
  }
  __syncthreads();
  if (t < 256) {                               // dstate[row] = q[row].z
    float d = 0.f;
    #pragma unroll
    for (int ii = 0; ii < 16; ++ii) d += (float)q_lds[t][ii] * z_lds[ii];
    dstate[t] = d;
  }

  const int wrow = w * 32;
  bf16x8 qf[2];
  #pragma unroll
  for (int mi = 0; mi < 2; ++mi) {
    bf16x8 v = {};
    if (lq < 2) v = *(const bf16x8*)&q_lds[wrow + mi * 16 + lr][lq * 8];
    qf[mi] = v;
  }
  f32x4 acc[2][8] = {};
  float den_l[2][4] = {};
  const int nc0 = (c == 0) ? 4 : 0;

  for (int nc = nc0; nc < 8; ++nc) {
    __syncthreads();                           // vt_lds reuse safe
    {                                          // stage V^T chunk [128 dv][64 keys]
      const int dv = t >> 2, kk = (t & 3) * 16;
      const int key0 = nc * 64;
      const int sg = (key0 < 256) ? (c - 1) * CC + key0 : c * CC + key0 - 256;
      const bf16_t* src = vT + ((size_t)((b * HH + h) * 128 + dv)) * SS + sg + kk;
      *(uint4*)&vt_lds[dv][kk]     = *(const uint4*)src;
      *(uint4*)&vt_lds[dv][kk + 8] = *(const uint4*)(src + 8);
    }
    __syncthreads();
    f32x4 attf[2][4];
    #pragma unroll
    for (int nf = 0; nf < 4; ++nf) {
      bf16x8 kv = {};
      if (lq < 2) kv = *(const bf16x8*)&k_lds[nc * 64 + nf * 16 + lr][lq * 8];
      #pragma unroll
      for (int mi = 0; mi < 2; ++mi) {
        const f32x4 zero = {0.f, 0.f, 0.f, 0.f};
        attf[mi][nf] = __builtin_amdgcn_mfma_f32_16x16x32_bf16(qf[mi], kv, zero, 0, 0, 0);
      }
    }
    #pragma unroll
    for (int mi = 0; mi < 2; ++mi)
      #pragma unroll
      for (int nf = 0; nf < 4; ++nf)
        #pragma unroll
        for (int r = 0; r < 4; ++r) {
          const int row_l = wrow + mi * 16 + lq * 4 + r;
          const int key_l = nc * 64 + nf * 16 + lr;
          float a = attf[mi][nf][r];
          if (key_l >= 256 && key_l - 256 > row_l) a = 0.f;
          den_l[mi][r] += a;
          p_lds[w][mi * 16 + lq * 4 + r][nf * 16 + lr] = (__bf16)a;
        }
    #pragma unroll
    for (int ks = 0; ks < 2; ++ks) {
      bf16x8 pa[2];
      #pragma unroll
      for (int mi = 0; mi < 2; ++mi)
        pa[mi] = *(const bf16x8*)&p_lds[w][mi * 16 + lr][ks * 32 + lq * 8];
      #pragma unroll
      for (int nf = 0; nf < 8; ++nf) {
        const bf16x8 vb = *(const bf16x8*)&vt_lds[nf * 16 + lr][ks * 32 + lq * 8];
        #pragma unroll
        for (int mi = 0; mi < 2; ++mi)
          acc[mi][nf] = __builtin_amdgcn_mfma_f32_16x16x32_bf16(pa[mi], vb, acc[mi][nf], 0, 0, 0);
      }
    }
  }

  if (c >= 2) {                                // state numerator: acc += q.S
    #pragma unroll
    for (int mi = 0; mi < 2; ++mi)
      for (int r = 0; r < 4; ++r) {
        const int row_l = wrow + mi * 16 + lq * 4 + r;
        float qrow[16];
        #pragma unroll
        for (int ii = 0; ii < 16; ++ii) qrow[ii] = (float)q_lds[row_l][ii];
        #pragma unroll
        for (int nf = 0; nf < 8; ++nf) {
          float sacc = 0.f;
          #pragma unroll
          for (int ii = 0; ii < 16; ++ii) sacc += qrow[ii] * s_f32[ii][nf * 16 + lr];
          acc[mi][nf][r] += sacc;
        }
      }
  }
  #pragma unroll
  for (int mi = 0; mi < 2; ++mi)
    #pragma unroll
    for (int r = 0; r < 4; ++r) {
      float d = den_l[mi][r];
      d += __shfl_xor(d, 1, 64); d += __shfl_xor(d, 2, 64);
      d += __shfl_xor(d, 4, 64); d += __shfl_xor(d, 8, 64);
      const int row_l = wrow + mi * 16 + lq * 4 + r;
      den_l[mi][r] = 1.0f / (d + dstate[row_l] + 1e-6f);
    }
  #pragma unroll
  for (int mi = 0; mi < 2; ++mi)
    #pragma unroll
    for (int r = 0; r < 4; ++r) {
      const size_t row_g = rowbase + wrow + mi * 16 + lq * 4 + r;
      const float inv = den_l[mi][r];
      #pragma unroll
      for (int nf = 0; nf < 8; ++nf)
        outp[row_g * DD + h * 128 + nf * 16 + lr] = (__bf16)(acc[mi][nf][r] * inv);
    }
}

// ---------------- LayerNorm (eps 1e-5) -> bf16 ----------------
__global__ __launch_bounds__(256) void ln_kernel(
    const float* __restrict__ hbuf, const float* __restrict__ g,
    const float* __restrict__ bta, bf16_t* __restrict__ out)
{
  const int row = blockIdx.x;
  const int t = threadIdx.x;
  const float4 x = ((const float4*)(hbuf + (size_t)row * DD))[t];
  float s  = x.x + x.y + x.z + x.w;
  float s2 = x.x*x.x + x.y*x.y + x.z*x.z + x.w*x.w;
  #pragma unroll
  for (int off = 32; off > 0; off >>= 1) {
    s  += __shfl_down(s,  off, 64);
    s2 += __shfl_down(s2, off, 64);
  }
  __shared__ float ws[8];
  if ((t & 63) == 0) { ws[(t >> 6) * 2] = s; ws[(t >> 6) * 2 + 1] = s2; }
  __syncthreads();
  const float ts  = ws[0] + ws[2] + ws[4] + ws[6];
  const float ts2 = ws[1] + ws[3] + ws[5] + ws[7];
  const float mu  = ts * (1.0f / DD);
  const float var = ts2 * (1.0f / DD) - mu * mu;
  const float inv = rsqrtf(var + 1e-5f);
  const float4 gv = ((const float4*)g)[t];
  const float4 bv = ((const float4*)bta)[t];
  bf16x4 o;
  o[0] = (__bf16)((x.x - mu) * inv * gv.x + bv.x);
  o[1] = (__bf16)((x.y - mu) * inv * gv.y + bv.y);
  o[2] = (__bf16)((x.z - mu) * inv * gv.z + bv.z);
  o[3] = (__bf16)((x.w - mu) * inv * gv.w + bv.w);
  *(bf16x4*)(out + (size_t)row * DD + t * 4) = o;
}

extern "C" void kernel_launch(void* const* d_in, const int* in_sizes, int n_in,
                              void* d_out, int out_size, void* d_ws, size_t ws_size,
                              hipStream_t stream) {
  (void)in_sizes; (void)n_in; (void)out_size; (void)ws_size;
  const int*   x    = (const int*)d_in[0];
  const float* emb  = (const float*)d_in[1];
  const float* Wq   = (const float*)d_in[2];
  const float* Wk   = (const float*)d_in[3];
  const float* Wv   = (const float*)d_in[4];
  const float* Wo   = (const float*)d_in[5];
  const float* ln_g = (const float*)d_in[6];
  const float* ln_b = (const float*)d_in[7];
  const float* outW = (const float*)d_in[8];
  const float* outb = (const float*)d_in[9];
  float* out = (float*)d_out;

  char* ws = (char*)d_ws;
  float*  ctx_f32 = (float*) (ws + 0);             // 33,554,432 (live till Wo)
  bf16_t* ctx_bf  = (bf16_t*)(ws + 33554432ull);   // 16,777,216 (dead after QKV)
  bf16_t* qbuf    = (bf16_t*)(ws + 50331648ull);   //  2,097,152
  bf16_t* kbuf    = (bf16_t*)(ws + 52428800ull);   //  2,097,152
  bf16_t* vTbuf   = (bf16_t*)(ws + 54525952ull);   // 16,777,216 (dead after attn)
  bf16_t* attn_bf = (bf16_t*)(ws + 71303168ull);   // 16,777,216 (reused as h_bf)
  float*  Gbuf    = (float*) (ws + 88080384ull);   //  2,097,152
  float*  KSbuf   = (float*) (ws + 90177536ull);   //     16,384
  bf16_t* WqkvT   = (bf16_t*)(ws + 90193920ull);   //  2,621,440
  bf16_t* WoT     = (bf16_t*)(ws + 92815360ull);   //  2,097,152
  bf16_t* outWT   = (bf16_t*)(ws + 94912512ull);   // 65,536,000 (end 160,448,512)
  float*  hbuf    = (float*) (ws + 33554432ull);   // 33,554,432 overlay (ctx_bf..vT dead)
  bf16_t* h_bf    = attn_bf;

  transpose_cvt<<<dim3(2, 16),   256, 0, stream>>>(Wq,   WqkvT,             DD, 128);
  transpose_cvt<<<dim3(2, 16),   256, 0, stream>>>(Wk,   WqkvT + 128 * DD,  DD, 128);
  transpose_cvt<<<dim3(16, 16),  256, 0, stream>>>(Wv,   WqkvT + 256 * DD,  DD, DD);
  transpose_cvt<<<dim3(16, 16),  256, 0, stream>>>(Wo,   WoT,               DD, DD);
  transpose_cvt<<<dim3(500, 16), 256, 0, stream>>>(outW, outWT,             DD, VV);

  ctx_kernel<<<BB * SS, 256, 0, stream>>>(x, emb, ctx_f32, ctx_bf);

  // QKV projection, epilogue: phi(q,k)->bf16 qb/kb, v->bf16 transposed vT
  gemm128_kernel<3><<<(1280 / 128) * (BB * SS / 128), 256, 0, stream>>>(
      ctx_bf, WqkvT, nullptr, nullptr, qbuf, kbuf, vTbuf, 1280, DD);

  gstate_kernel<<<BB * NC * HH, 64, 0, stream>>>(kbuf, vTbuf, Gbuf, KSbuf);
  attn_kernel<<<BB * NC * HH, 512, 0, stream>>>(qbuf, kbuf, vTbuf, Gbuf, KSbuf, attn_bf);

  // out-proj + residual
  gemm128_kernel<2><<<(DD / 128) * (BB * SS / 128), 256, 0, stream>>>(
      attn_bf, WoT, hbuf, ctx_f32, nullptr, nullptr, nullptr, DD, DD);

  ln_kernel<<<BB * SS, 256, 0, stream>>>(hbuf, ln_g, ln_b, h_bf);

  // logits + bias
  gemm128_kernel<1><<<(VV / 128) * (BB * SS / 128), 256, 0, stream>>>(
      h_bf, outWT, out, outb, nullptr, nullptr, nullptr, VV, DD);
}

// Round 11
// 784.098 us; speedup vs baseline: 1.4125x; 1.0423x over previous
//
#include <hip/hip_runtime.h>
#include <hip/hip_bf16.h>

typedef __bf16 bf16_t;
typedef __bf16 bf16x4 __attribute__((ext_vector_type(4)));
typedef __bf16 bf16x8 __attribute__((ext_vector_type(8)));
typedef float f32x4 __attribute__((ext_vector_type(4)));

#define BB 2
#define SS 4096
#define DD 1024
#define VV 32000
#define HH 8
#define CC 256
#define NC 16

#define GLD_LDS16(gp, lp) __builtin_amdgcn_global_load_lds( \
    (const __attribute__((address_space(1))) void*)(gp),    \
    (__attribute__((address_space(3))) void*)(lp), 16, 0, 0)

// ---------------- ctx: emb gather + 4-tap causal sum (bf16 only) ----------------
__global__ __launch_bounds__(256) void ctx_kernel(
    const int* __restrict__ x, const float* __restrict__ emb,
    bf16_t* __restrict__ ctxb)
{
  const int row = blockIdx.x;            // b*SS + s
  const int b = row >> 12, s = row & (SS - 1);
  const int t = threadIdx.x;             // d = t*4
  float4 a = make_float4(0.f, 0.f, 0.f, 0.f);
  #pragma unroll
  for (int o = 0; o < 4; ++o) {
    if (s - o >= 0) {
      const int idx = x[b * SS + s - o];
      const float4 e = *(const float4*)(emb + (size_t)idx * DD + t * 4);
      a.x += e.x; a.y += e.y; a.z += e.z; a.w += e.w;
    }
  }
  bf16x4 bv;
  bv[0] = (__bf16)a.x; bv[1] = (__bf16)a.y; bv[2] = (__bf16)a.z; bv[3] = (__bf16)a.w;
  *(bf16x4*)(ctxb + (size_t)row * DD + t * 4) = bv;
}

// ------- transpose + f32->bf16, 128x64 tile: dst[c][r]=src[r][c], 256B dst writes -------
__global__ __launch_bounds__(256) void transpose_cvt(
    const float* __restrict__ src, bf16_t* __restrict__ dst,
    int srcRows, int srcCols)
{
  __shared__ __align__(16) float tile[128][65];
  const int c0 = blockIdx.x * 64, r0 = blockIdx.y * 128;
  const int t = threadIdx.x;
  #pragma unroll
  for (int p = 0; p < 8; ++p) {
    const int r = p * 16 + (t >> 4);
    const int c = (t & 15) * 4;
    *(float4*)&tile[r][c] = *(const float4*)(src + (size_t)(r0 + r) * srcCols + c0 + c);
  }
  __syncthreads();
  #pragma unroll
  for (int p = 0; p < 4; ++p) {
    const int j = p * 16 + (t >> 4);     // dst row (src col)
    const int i0 = (t & 15) * 8;         // src row offset
    bf16x8 v;
    #pragma unroll
    for (int e = 0; e < 8; ++e) v[e] = (__bf16)tile[i0 + e][j];
    *(bf16x8*)(dst + (size_t)(c0 + j) * srcRows + r0 + i0) = v;
  }
}

// ========== m97-structure 128x128 GEMM, BK=64, 4 waves, 4 blocks/CU ==========
// (R10 core, unchanged.) EPI: 1 = +bias[col] -> f32 C (logits);
// 2 = +bf16 residual -> bf16 Cb (Wo out, pre-LN h); 3 = QKV epilogue.
template<int EPI>
__global__ __launch_bounds__(256, 4) void gemm128_kernel(
    const bf16_t* __restrict__ A, const bf16_t* __restrict__ BT,
    float* __restrict__ C, bf16_t* __restrict__ Cb,
    const float* __restrict__ extraF, const bf16_t* __restrict__ extraB,
    bf16_t* __restrict__ qb, bf16_t* __restrict__ kbx, bf16_t* __restrict__ vtb,
    int N, int K)
{
  __shared__ __align__(16) bf16_t As[128 * 64];
  __shared__ __align__(16) bf16_t Bs[128 * 64];
  const int bid = blockIdx.x;
  const int i = bid >> 3, xcd = bid & 7;
  const int by = xcd * 8 + (i & 7);          // GY = M/128 = 64 always
  const int bx = i >> 3;
  const int n0 = bx * 128, m0 = by * 128;
  const int t = threadIdx.x;
  const int w = t >> 6, lane = t & 63;
  const int wm = (w >> 1) * 64, wn = (w & 1) * 64;
  const int lr = lane & 15, lq = lane >> 4;
  f32x4 acc[4][4] = {};

  for (int k0 = 0; k0 < K; k0 += 64) {
    #pragma unroll
    for (int j = 0; j < 4; ++j) {
      const int idx = j * 256 + t;
      const int r = idx >> 3;
      const int sc = ((idx & 7) ^ (r & 7)) * 8;      // pre-swizzled src col
      GLD_LDS16(A  + (size_t)(m0 + r) * K + k0 + sc, As + (size_t)idx * 8);
      GLD_LDS16(BT + (size_t)(n0 + r) * K + k0 + sc, Bs + (size_t)idx * 8);
    }
    asm volatile("s_waitcnt vmcnt(0)" ::: "memory");
    __syncthreads();
    bf16x8 af[4][2], bfr[4][2];
    #pragma unroll
    for (int ii = 0; ii < 4; ++ii) {
      const int ra = wm + ii * 16 + lr;
      const int rb = wn + ii * 16 + lr;
      #pragma unroll
      for (int ks = 0; ks < 2; ++ks) {
        const int col = ((ks * 4 + lq) ^ (lr & 7)) * 8;   // swizzled read col
        af[ii][ks]  = *(const bf16x8*)(As + ra * 64 + col);
        bfr[ii][ks] = *(const bf16x8*)(Bs + rb * 64 + col);
      }
    }
    #pragma unroll
    for (int mi = 0; mi < 4; ++mi)
      #pragma unroll
      for (int ni = 0; ni < 4; ++ni) {
        acc[mi][ni] = __builtin_amdgcn_mfma_f32_16x16x32_bf16(af[mi][0], bfr[ni][0], acc[mi][ni], 0, 0, 0);
        acc[mi][ni] = __builtin_amdgcn_mfma_f32_16x16x32_bf16(af[mi][1], bfr[ni][1], acc[mi][ni], 0, 0, 0);
      }
    __syncthreads();
  }

  // C/D layout: col=lane&15, row=(lane>>4)*4+reg  [m89-verified]
  if (EPI == 3) {
    #pragma unroll
    for (int mi = 0; mi < 4; ++mi) {
      const int row0 = m0 + wm + mi * 16 + lq * 4;
      #pragma unroll
      for (int ni = 0; ni < 4; ++ni) {
        const int col = n0 + wn + ni * 16 + lr;
        if (col < 256) {                       // q | k : phi -> bf16 (block-uniform)
          #pragma unroll
          for (int r = 0; r < 4; ++r) {
            float v = acc[mi][ni][r];
            v = v > 0.f ? v + 1.f : __expf(v);
            if (col < 128) qb [(size_t)(row0 + r) * 128 + col      ] = (__bf16)v;
            else           kbx[(size_t)(row0 + r) * 128 + col - 128] = (__bf16)v;
          }
        } else {                               // v -> transposed bf16
          const int vcol = col - 256;
          const int hh = vcol >> 7, dv = vcol & 127;
          const int bb = row0 >> 12, s0 = row0 & (SS - 1);
          bf16x4 pv;
          #pragma unroll
          for (int r = 0; r < 4; ++r) pv[r] = (__bf16)acc[mi][ni][r];
          *(bf16x4*)(vtb + ((size_t)((bb * HH + hh) * 128 + dv)) * SS + s0) = pv;
        }
      }
    }
    return;
  }
  #pragma unroll
  for (int mi = 0; mi < 4; ++mi) {
    #pragma unroll
    for (int r = 0; r < 4; ++r) {
      const int row = m0 + wm + mi * 16 + lq * 4 + r;
      #pragma unroll
      for (int ni = 0; ni < 4; ++ni) {
        const int col = n0 + wn + ni * 16 + lr;
        float v = acc[mi][ni][r];
        if (EPI == 1) {
          v += extraF[col];
          __builtin_nontemporal_store(v, &C[(size_t)row * N + col]);
        }
        if (EPI == 2) {
          v += (float)extraB[(size_t)row * N + col];
          Cb[(size_t)row * N + col] = (__bf16)v;
        }
      }
    }
  }
}

// ---------------- per-chunk G = K^T V (MFMA) and ksum ----------------
__global__ __launch_bounds__(64) void gstate_kernel(
    const bf16_t* __restrict__ kb, const bf16_t* __restrict__ vT,
    float* __restrict__ G, float* __restrict__ KS)
{
  const int bid = blockIdx.x;                  // b*128 + c*8 + h
  const int h = bid & 7, c = (bid >> 3) & 15, b = bid >> 7;
  const int lane = threadIdx.x;
  const int lr = lane & 15, lq = lane >> 4;
  __shared__ __align__(16) bf16_t ktl[16][264]; // k transposed: [i][s]
  for (int ss = 0; ss < 4; ++ss) {
    const int s = ss * 64 + lane;
    const bf16_t* src = kb + (size_t)(b * SS + c * CC + s) * 128 + h * 16;
    const bf16x8 v0 = *(const bf16x8*)src;
    const bf16x8 v1 = *(const bf16x8*)(src + 8);
    #pragma unroll
    for (int ii = 0; ii < 8; ++ii) { ktl[ii][s] = v0[ii]; ktl[8 + ii][s] = v1[ii]; }
  }
  __syncthreads();
  if (lane < 16) {
    float ks = 0.f;
    for (int s = 0; s < 256; ++s) ks += (float)ktl[lane][s];
    KS[((size_t)((b * NC + c) * HH + h)) * 16 + lane] = ks;
  }
  bf16x8 af[8];
  #pragma unroll
  for (int sk = 0; sk < 8; ++sk)
    af[sk] = *(const bf16x8*)&ktl[lr][sk * 32 + lq * 8];
  float* gout = G + ((size_t)((b * NC + c) * HH + h)) * 2048;
  #pragma unroll
  for (int nf = 0; nf < 8; ++nf) {
    f32x4 acc = {0.f, 0.f, 0.f, 0.f};
    #pragma unroll
    for (int sk = 0; sk < 8; ++sk) {
      const bf16x8 vb = *(const bf16x8*)(vT +
          ((size_t)((b * HH + h) * 128 + nf * 16 + lr)) * SS + c * CC + sk * 32 + lq * 8);
      acc = __builtin_amdgcn_mfma_f32_16x16x32_bf16(af[sk], vb, acc, 0, 0, 0);
    }
    #pragma unroll
    for (int r = 0; r < 4; ++r)
      gout[(size_t)(lq * 4 + r) * 128 + nf * 16 + lr] = acc[r];
  }
}

// ---------------- MFMA attention: intra(masked) + bypass + state ----------------
__global__ __launch_bounds__(512, 2) void attn_kernel(
    const bf16_t* __restrict__ qb, const bf16_t* __restrict__ kb,
    const bf16_t* __restrict__ vT, const float* __restrict__ Gb,
    const float* __restrict__ KS, bf16_t* __restrict__ outp)
{
  const int bid = blockIdx.x;                  // b*128 + c*8 + h
  const int h = bid & 7, c = (bid >> 3) & 15, b = bid >> 7;
  const int t = threadIdx.x;
  const int w = t >> 6, lane = t & 63;
  const int lr = lane & 15, lq = lane >> 4;
  const int rowbase = b * SS + c * CC;

  __shared__ __align__(16) bf16_t q_lds[256][24];
  __shared__ __align__(16) bf16_t k_lds[512][24];
  __shared__ __align__(16) bf16_t vt_lds[128][72];
  __shared__ __align__(16) bf16_t p_lds[8][32][72];
  __shared__ float s_f32[16][128];
  __shared__ float z_lds[16];
  __shared__ float dstate[256];

  if (t < 256) {                               // stage q rows (bf16, 32B each)
    const bf16_t* src = qb + (size_t)(rowbase + t) * 128 + h * 16;
    *(uint4*)&q_lds[t][0] = *(const uint4*)src;
    *(uint4*)&q_lds[t][8] = *(const uint4*)(src + 8);
  }
  {                                            // stage k rows: prev | cur
    if (t < 256 && c == 0) {
      const uint4 z = {0u, 0u, 0u, 0u};
      *(uint4*)&k_lds[t][0] = z; *(uint4*)&k_lds[t][8] = z;
    } else {
      const int sg = (t < 256) ? (c - 1) * CC + t : c * CC + (t - 256);
      const bf16_t* src = kb + (size_t)(b * SS + sg) * 128 + h * 16;
      *(uint4*)&k_lds[t][0] = *(const uint4*)src;
      *(uint4*)&k_lds[t][8] = *(const uint4*)(src + 8);
    }
  }
  if (t < 16) {                                // z[i] = sum_{j<=c-2} ksum_j[i]
    float z = 0.f;
    for (int j = 0; j + 2 <= c; ++j) z += KS[((size_t)((b * NC + j) * HH + h)) * 16 + t];
    z_lds[t] = z;
  }
  if (c >= 2) {                                // S = sum_{j<=c-2} G_j
    for (int idx = t; idx < 2048; idx += 512) {
      float sv = 0.f;
      for (int j = 0; j + 2 <= c; ++j)
        sv += Gb[((size_t)((b * NC + j) * HH + h)) * 2048 + idx];
      ((float*)s_f32)[idx] = sv;
    }
  }
  __syncthreads();
  if (t < 256) {                               // dstate[row] = q[row].z
    float d = 0.f;
    #pragma unroll
    for (int ii = 0; ii < 16; ++ii) d += (float)q_lds[t][ii] * z_lds[ii];
    dstate[t] = d;
  }

  const int wrow = w * 32;
  bf16x8 qf[2];
  #pragma unroll
  for (int mi = 0; mi < 2; ++mi) {
    bf16x8 v = {};
    if (lq < 2) v = *(const bf16x8*)&q_lds[wrow + mi * 16 + lr][lq * 8];
    qf[mi] = v;
  }
  f32x4 acc[2][8] = {};
  float den_l[2][4] = {};
  const int nc0 = (c == 0) ? 4 : 0;

  for (int nc = nc0; nc < 8; ++nc) {
    __syncthreads();                           // vt_lds reuse safe
    {                                          // stage V^T chunk [128 dv][64 keys]
      const int dv = t >> 2, kk = (t & 3) * 16;
      const int key0 = nc * 64;
      const int sg = (key0 < 256) ? (c - 1) * CC + key0 : c * CC + key0 - 256;
      const bf16_t* src = vT + ((size_t)((b * HH + h) * 128 + dv)) * SS + sg + kk;
      *(uint4*)&vt_lds[dv][kk]     = *(const uint4*)src;
      *(uint4*)&vt_lds[dv][kk + 8] = *(const uint4*)(src + 8);
    }
    __syncthreads();
    f32x4 attf[2][4];
    #pragma unroll
    for (int nf = 0; nf < 4; ++nf) {
      bf16x8 kv = {};
      if (lq < 2) kv = *(const bf16x8*)&k_lds[nc * 64 + nf * 16 + lr][lq * 8];
      #pragma unroll
      for (int mi = 0; mi < 2; ++mi) {
        const f32x4 zero = {0.f, 0.f, 0.f, 0.f};
        attf[mi][nf] = __builtin_amdgcn_mfma_f32_16x16x32_bf16(qf[mi], kv, zero, 0, 0, 0);
      }
    }
    #pragma unroll
    for (int mi = 0; mi < 2; ++mi)
      #pragma unroll
      for (int nf = 0; nf < 4; ++nf)
        #pragma unroll
        for (int r = 0; r < 4; ++r) {
          const int row_l = wrow + mi * 16 + lq * 4 + r;
          const int key_l = nc * 64 + nf * 16 + lr;
          float a = attf[mi][nf][r];
          if (key_l >= 256 && key_l - 256 > row_l) a = 0.f;
          den_l[mi][r] += a;
          p_lds[w][mi * 16 + lq * 4 + r][nf * 16 + lr] = (__bf16)a;
        }
    #pragma unroll
    for (int ks = 0; ks < 2; ++ks) {
      bf16x8 pa[2];
      #pragma unroll
      for (int mi = 0; mi < 2; ++mi)
        pa[mi] = *(const bf16x8*)&p_lds[w][mi * 16 + lr][ks * 32 + lq * 8];
      #pragma unroll
      for (int nf = 0; nf < 8; ++nf) {
        const bf16x8 vb = *(const bf16x8*)&vt_lds[nf * 16 + lr][ks * 32 + lq * 8];
        #pragma unroll
        for (int mi = 0; mi < 2; ++mi)
          acc[mi][nf] = __builtin_amdgcn_mfma_f32_16x16x32_bf16(pa[mi], vb, acc[mi][nf], 0, 0, 0);
      }
    }
  }

  if (c >= 2) {                                // state numerator: acc += q.S
    #pragma unroll
    for (int mi = 0; mi < 2; ++mi)
      for (int r = 0; r < 4; ++r) {
        const int row_l = wrow + mi * 16 + lq * 4 + r;
        float qrow[16];
        #pragma unroll
        for (int ii = 0; ii < 16; ++ii) qrow[ii] = (float)q_lds[row_l][ii];
        #pragma unroll
        for (int nf = 0; nf < 8; ++nf) {
          float sacc = 0.f;
          #pragma unroll
          for (int ii = 0; ii < 16; ++ii) sacc += qrow[ii] * s_f32[ii][nf * 16 + lr];
          acc[mi][nf][r] += sacc;
        }
      }
  }
  #pragma unroll
  for (int mi = 0; mi < 2; ++mi)
    #pragma unroll
    for (int r = 0; r < 4; ++r) {
      float d = den_l[mi][r];
      d += __shfl_xor(d, 1, 64); d += __shfl_xor(d, 2, 64);
      d += __shfl_xor(d, 4, 64); d += __shfl_xor(d, 8, 64);
      const int row_l = wrow + mi * 16 + lq * 4 + r;
      den_l[mi][r] = 1.0f / (d + dstate[row_l] + 1e-6f);
    }
  #pragma unroll
  for (int mi = 0; mi < 2; ++mi)
    #pragma unroll
    for (int r = 0; r < 4; ++r) {
      const size_t row_g = rowbase + wrow + mi * 16 + lq * 4 + r;
      const float inv = den_l[mi][r];
      #pragma unroll
      for (int nf = 0; nf < 8; ++nf)
        outp[row_g * DD + h * 128 + nf * 16 + lr] = (__bf16)(acc[mi][nf][r] * inv);
    }
}

// ---------------- LayerNorm (eps 1e-5), bf16 in -> bf16 out ----------------
__global__ __launch_bounds__(256) void ln_kernel(
    const bf16_t* __restrict__ hb, const float* __restrict__ g,
    const float* __restrict__ bta, bf16_t* __restrict__ out)
{
  const int row = blockIdx.x;
  const int t = threadIdx.x;
  const bf16x4 xb = *(const bf16x4*)(hb + (size_t)row * DD + t * 4);
  float4 x = make_float4((float)xb[0], (float)xb[1], (float)xb[2], (float)xb[3]);
  float s  = x.x + x.y + x.z + x.w;
  float s2 = x.x*x.x + x.y*x.y + x.z*x.z + x.w*x.w;
  #pragma unroll
  for (int off = 32; off > 0; off >>= 1) {
    s  += __shfl_down(s,  off, 64);
    s2 += __shfl_down(s2, off, 64);
  }
  __shared__ float ws[8];
  if ((t & 63) == 0) { ws[(t >> 6) * 2] = s; ws[(t >> 6) * 2 + 1] = s2; }
  __syncthreads();
  const float ts  = ws[0] + ws[2] + ws[4] + ws[6];
  const float ts2 = ws[1] + ws[3] + ws[5] + ws[7];
  const float mu  = ts * (1.0f / DD);
  const float var = ts2 * (1.0f / DD) - mu * mu;
  const float inv = rsqrtf(var + 1e-5f);
  const float4 gv = ((const float4*)g)[t];
  const float4 bv = ((const float4*)bta)[t];
  bf16x4 o;
  o[0] = (__bf16)((x.x - mu) * inv * gv.x + bv.x);
  o[1] = (__bf16)((x.y - mu) * inv * gv.y + bv.y);
  o[2] = (__bf16)((x.z - mu) * inv * gv.z + bv.z);
  o[3] = (__bf16)((x.w - mu) * inv * gv.w + bv.w);
  *(bf16x4*)(out + (size_t)row * DD + t * 4) = o;
}

extern "C" void kernel_launch(void* const* d_in, const int* in_sizes, int n_in,
                              void* d_out, int out_size, void* d_ws, size_t ws_size,
                              hipStream_t stream) {
  (void)in_sizes; (void)n_in; (void)out_size; (void)ws_size;
  const int*   x    = (const int*)d_in[0];
  const float* emb  = (const float*)d_in[1];
  const float* Wq   = (const float*)d_in[2];
  const float* Wk   = (const float*)d_in[3];
  const float* Wv   = (const float*)d_in[4];
  const float* Wo   = (const float*)d_in[5];
  const float* ln_g = (const float*)d_in[6];
  const float* ln_b = (const float*)d_in[7];
  const float* outW = (const float*)d_in[8];
  const float* outb = (const float*)d_in[9];
  float* out = (float*)d_out;

  char* ws = (char*)d_ws;
  bf16_t* ctx_bf  = (bf16_t*)(ws + 0);             // 16,777,216 (live till Wo residual)
  bf16_t* qbuf    = (bf16_t*)(ws + 16777216ull);   //  2,097,152
  bf16_t* kbuf    = (bf16_t*)(ws + 18874368ull);   //  2,097,152
  bf16_t* vTbuf   = (bf16_t*)(ws + 20971520ull);   // 16,777,216
  bf16_t* attn_bf = (bf16_t*)(ws + 37748736ull);   // 16,777,216 (attn out / Wo A; reused as h_bf)
  bf16_t* h_pre   = (bf16_t*)(ws + 54525952ull);   // 16,777,216 (Wo out, LN in)
  float*  Gbuf    = (float*) (ws + 71303168ull);   //  2,097,152
  float*  KSbuf   = (float*) (ws + 73400320ull);   //     16,384
  bf16_t* WqkvT   = (bf16_t*)(ws + 73416704ull);   //  2,621,440
  bf16_t* WoT     = (bf16_t*)(ws + 76038144ull);   //  2,097,152
  bf16_t* outWT   = (bf16_t*)(ws + 78135296ull);   // 65,536,000  (end 143,671,296)
  bf16_t* h_bf    = attn_bf;                       // LN out overlays attn_bf (dead after Wo)

  transpose_cvt<<<dim3(2, 8),   256, 0, stream>>>(Wq,   WqkvT,             DD, 128);
  transpose_cvt<<<dim3(2, 8),   256, 0, stream>>>(Wk,   WqkvT + 128 * DD,  DD, 128);
  transpose_cvt<<<dim3(16, 8),  256, 0, stream>>>(Wv,   WqkvT + 256 * DD,  DD, DD);
  transpose_cvt<<<dim3(16, 8),  256, 0, stream>>>(Wo,   WoT,               DD, DD);
  transpose_cvt<<<dim3(500, 8), 256, 0, stream>>>(outW, outWT,             DD, VV);

  ctx_kernel<<<BB * SS, 256, 0, stream>>>(x, emb, ctx_bf);

  // QKV projection, epilogue: phi(q,k)->bf16 qb/kb, v->bf16 transposed vT
  gemm128_kernel<3><<<(1280 / 128) * (BB * SS / 128), 256, 0, stream>>>(
      ctx_bf, WqkvT, nullptr, nullptr, nullptr, nullptr, qbuf, kbuf, vTbuf, 1280, DD);

  gstate_kernel<<<BB * NC * HH, 64, 0, stream>>>(kbuf, vTbuf, Gbuf, KSbuf);
  attn_kernel<<<BB * NC * HH, 512, 0, stream>>>(qbuf, kbuf, vTbuf, Gbuf, KSbuf, attn_bf);

  // out-proj + bf16 residual -> bf16 h_pre
  gemm128_kernel<2><<<(DD / 128) * (BB * SS / 128), 256, 0, stream>>>(
      attn_bf, WoT, nullptr, h_pre, nullptr, ctx_bf, nullptr, nullptr, nullptr, DD, DD);

  ln_kernel<<<BB * SS, 256, 0, stream>>>(h_pre, ln_g, ln_b, h_bf);

  // logits + bias (f32 out, nontemporal)
  gemm128_kernel<1><<<(VV / 128) * (BB * SS / 128), 256, 0, stream>>>(
      h_bf, outWT, out, nullptr, outb, nullptr, nullptr, nullptr, nullptr, VV, DD);
}